// Round 7
// baseline (86.177 us; speedup 1.0000x reference)
//
#include <hip/hip_runtime.h>
#include <hip/hip_cooperative_groups.h>
#include <math.h>

namespace cg = cooperative_groups;

// ---------------- constants (atomic units) ----------------
constexpr double B2A   = 0.52917721067;
constexpr double H2KJ  = 2625.499638;
constexpr float  RCUT2F = (float)((10.0 / B2A) * (10.0 / B2A));

constexpr double Zc_[2]   = {3.61565, 0.93619};
constexpr double MONO_[2] = {-0.390896, 0.195448};
constexpr double QSH_[2]  = {MONO_[0] - Zc_[0], MONO_[1] - Zc_[1]};
constexpr double DIPO_[2][3] = {{0.0, 0.0, -0.094298},
                                {0.0910288, 0.0, -0.207851}};
constexpr double QS_[2][5] = {{-0.330685, 0.0, 0.0, 0.869923, 0.0},
                              {-0.0739388, 0.0929482, 0.0, 0.00532425, 0.0}};
constexpr double B_EL_[2]  = {2.13358, 2.33322};
constexpr double B_PA_[2]  = {2.1975, 1.96474};
constexpr double SPA_[2]   = {6.50923, 0.527804};
constexpr double KD_PA_[2] = {-5.61925, -0.515584};
constexpr double KQ_PA_[2] = {-1.56567, -0.440164};
constexpr double C6_[2]    = {35.8289, 1.98954};
constexpr double B_D_[2]   = {1.84302, 1.30993};
constexpr double AD_[2][3] = {{4.45992, 6.07259, 4.55391},
                              {2.22001, 1.66835, 0.183855}};
constexpr double ETA_[2]   = {6.18699e-06 * 2.0, 0.561535 * 2.0};
constexpr double B_XP_[2]  = {2.73582, 2.04028};
constexpr double SXP_[2]   = {1.26592, 0.200089};
constexpr double B_CT_[2]  = {1.89485, 2.36763};
constexpr double SACC_[2]  = {-0.67857, 1.36735};
constexpr double SDON_[2]  = {0.757752, 0.00888982};
constexpr double KD_DO_[2] = {-0.512036, -0.0511668};
constexpr double KQ_DO_[2] = {-0.208186, 0.0568152};
constexpr double EPS_OFF = 0.380979;

constexpr double D_M   = 524.265 / H2KJ;
constexpr double K_B   = 5098.15 / H2KJ * B2A * B2A;
constexpr double B_EQ  = 0.958413 / B2A;
constexpr double K_BB  = -61.1423 / H2KJ * B2A * B2A;
constexpr double K_BA  = -159.886 / H2KJ * B2A;
constexpr double TH_EQ = 104.4234 * M_PI / 180.0;
constexpr double K_TH  = 452.183 / H2KJ;
constexpr double SQ32  = 0.86602540378443864676;

// local-frame quadrupole (traceless Cartesian), /3 folded; q21s=q22s=0 -> only xx,yy,zz,xz
constexpr double QLXX_[2] = {(-0.5 * QS_[0][0] + SQ32 * QS_[0][3]) / 3.0,
                             (-0.5 * QS_[1][0] + SQ32 * QS_[1][3]) / 3.0};
constexpr double QLYY_[2] = {(-0.5 * QS_[0][0] - SQ32 * QS_[0][3]) / 3.0,
                             (-0.5 * QS_[1][0] - SQ32 * QS_[1][3]) / 3.0};
constexpr double QLZZ_[2] = {QS_[0][0] / 3.0, QS_[1][0] / 3.0};
constexpr double QLXZ_[2] = {SQ32 * QS_[0][1] / 3.0, SQ32 * QS_[1][1] / 3.0};
constexpr double DIP0_[2] = {DIPO_[0][0], DIPO_[1][0]};
constexpr double DIP2_[2] = {DIPO_[0][2], DIPO_[1][2]};

#define MAXN 768
#define NWAVE 4
#define TF(A, t) ((t) ? (float)A[1] : (float)A[0])
#define S(x) (tb ? x##1 : x##0)

// ---------------- f32 vec helpers ----------------
struct f3 { float x, y, z; };
__device__ inline f3 operator-(f3 a, f3 b) { return {a.x - b.x, a.y - b.y, a.z - b.z}; }
__device__ inline f3 operator+(f3 a, f3 b) { return {a.x + b.x, a.y + b.y, a.z + b.z}; }
__device__ inline f3 operator*(f3 a, float s) { return {a.x * s, a.y * s, a.z * s}; }
__device__ inline float dotf(f3 a, f3 b) { return a.x * b.x + a.y * b.y + a.z * b.z; }
__device__ inline f3 crossf(f3 a, f3 b) {
    return {a.y * b.z - a.z * b.y, a.z * b.x - a.x * b.z, a.x * b.y - a.y * b.x};
}
__device__ inline f3 normf(f3 a) { float s = rsqrtf(dotf(a, a)); return a * s; }
__device__ inline f3 getcf(const float* c, int i) {
    return {c[3 * i], c[3 * i + 1], c[3 * i + 2]};
}
__device__ inline void load_boxf(const float* box, float bx[3][3], float bi[3][3]) {
    for (int i = 0; i < 3; ++i)
        for (int j = 0; j < 3; ++j) bx[i][j] = box[i * 3 + j];
    float a = bx[0][0], b = bx[0][1], c = bx[0][2];
    float d = bx[1][0], e = bx[1][1], f = bx[1][2];
    float g = bx[2][0], h = bx[2][1], i2 = bx[2][2];
    float A =  (e * i2 - f * h), B = -(d * i2 - f * g), C =  (d * h - e * g);
    float D = -(b * i2 - c * h), E =  (a * i2 - c * g), F = -(a * h - b * g);
    float G =  (b * f - c * e),  H = -(a * f - c * d),  I =  (a * e - b * d);
    float s = 1.0f / (a * A + b * B + c * C);
    bi[0][0] = A * s; bi[0][1] = D * s; bi[0][2] = G * s;
    bi[1][0] = B * s; bi[1][1] = E * s; bi[1][2] = H * s;
    bi[2][0] = C * s; bi[2][1] = F * s; bi[2][2] = I * s;
}
__device__ inline f3 pbcf(f3 d, const float bx[3][3], const float bi[3][3]) {
    float s0 = rintf(d.x * bi[0][0] + d.y * bi[1][0] + d.z * bi[2][0]);
    float s1 = rintf(d.x * bi[0][1] + d.y * bi[1][1] + d.z * bi[2][1]);
    float s2 = rintf(d.x * bi[0][2] + d.y * bi[1][2] + d.z * bi[2][2]);
    d.x -= s0 * bx[0][0] + s1 * bx[1][0] + s2 * bx[2][0];
    d.y -= s0 * bx[0][1] + s1 * bx[1][1] + s2 * bx[2][1];
    d.z -= s0 * bx[0][2] + s1 * bx[1][2] + s2 * bx[2][2];
    return d;
}
__device__ inline float f1mf(float u) { return -__expf(-u) * (1.0f + 0.5f * u); }  // f1 - 1

// ---------------- f64 helpers (bonded terms only) ----------------
struct d3 { double x, y, z; };
__device__ inline d3 subd(d3 a, d3 b) { return {a.x - b.x, a.y - b.y, a.z - b.z}; }
__device__ inline double dotd(d3 a, d3 b) { return a.x * b.x + a.y * b.y + a.z * b.z; }
__device__ inline d3 getcd(const float* c, int i) {
    return {(double)c[3 * i], (double)c[3 * i + 1], (double)c[3 * i + 2]};
}
__device__ inline void load_boxd(const float* box, double bx[3][3], double bi[3][3]) {
    for (int i = 0; i < 3; ++i)
        for (int j = 0; j < 3; ++j) bx[i][j] = (double)box[i * 3 + j];
    double a = bx[0][0], b = bx[0][1], c = bx[0][2];
    double d = bx[1][0], e = bx[1][1], f = bx[1][2];
    double g = bx[2][0], h = bx[2][1], i2 = bx[2][2];
    double A =  (e * i2 - f * h), B = -(d * i2 - f * g), C =  (d * h - e * g);
    double D = -(b * i2 - c * h), E =  (a * i2 - c * g), F = -(a * h - b * g);
    double G =  (b * f - c * e),  H = -(a * f - c * d),  I =  (a * e - b * d);
    double s = 1.0 / (a * A + b * B + c * C);
    bi[0][0] = A * s; bi[0][1] = D * s; bi[0][2] = G * s;
    bi[1][0] = B * s; bi[1][1] = E * s; bi[1][2] = H * s;
    bi[2][0] = C * s; bi[2][1] = F * s; bi[2][2] = I * s;
}
__device__ inline d3 pbcd(d3 d, const double bx[3][3], const double bi[3][3]) {
    double s0 = rint(d.x * bi[0][0] + d.y * bi[1][0] + d.z * bi[2][0]);
    double s1 = rint(d.x * bi[0][1] + d.y * bi[1][1] + d.z * bi[2][1]);
    double s2 = rint(d.x * bi[0][2] + d.y * bi[1][2] + d.z * bi[2][2]);
    d.x -= s0 * bx[0][0] + s1 * bx[1][0] + s2 * bx[2][0];
    d.y -= s0 * bx[0][1] + s1 * bx[1][1] + s2 * bx[2][1];
    d.z -= s0 * bx[0][2] + s1 * bx[1][2] + s2 * bx[2][2];
    return d;
}

// ---------------- frame (local axes) ----------------
__device__ inline void calc_frame(const float* coords, const float bx[3][3],
                                  const float bi[3][3], int n, float R[3][3], int* tt) {
    int w = n / 3, m = n - w * 3, o = w * 3;
    int zat = (m == 0) ? n + 1 : o;
    int xat = (m == 0) ? n + 2 : ((m == 1) ? n + 1 : n - 1);
    f3 cn = getcf(coords, n);
    f3 uz = normf(pbcf(getcf(coords, zat) - cn, bx, bi));
    f3 ux = normf(pbcf(getcf(coords, xat) - cn, bx, bi));
    f3 zax = (m == 0) ? normf(uz + ux) : uz;
    f3 xax = normf(ux - zax * dotf(ux, zax));
    f3 yax = crossf(zax, xax);
    R[0][0] = xax.x; R[0][1] = yax.x; R[0][2] = zax.x;
    R[1][0] = xax.y; R[1][1] = yax.y; R[1][2] = zax.y;
    R[2][0] = xax.z; R[2][1] = yax.z; R[2][2] = zax.z;
    *tt = (m == 0) ? 0 : 1;
}

// rotated multipoles: M = [mu0,mu1,mu2, Qxx,Qxy,Qxz,Qyy,Qyz,Qzz]
__device__ inline void rot_muQ(const float R[3][3], int t, float M[9]) {
    float d0 = TF(DIP0_, t), d2 = TF(DIP2_, t);
    M[0] = R[0][0] * d0 + R[0][2] * d2;
    M[1] = R[1][0] * d0 + R[1][2] * d2;
    M[2] = R[2][0] * d0 + R[2][2] * d2;
    float qlxx = TF(QLXX_, t), qlyy = TF(QLYY_, t), qlzz = TF(QLZZ_, t), qlxz = TF(QLXZ_, t);
    float Bq[3][3];
    for (int p = 0; p < 3; ++p) {
        Bq[p][0] = R[p][0] * qlxx + R[p][2] * qlxz;
        Bq[p][1] = R[p][1] * qlyy;
        Bq[p][2] = R[p][0] * qlxz + R[p][2] * qlzz;
    }
    M[3] = Bq[0][0] * R[0][0] + Bq[0][1] * R[0][1] + Bq[0][2] * R[0][2];
    M[4] = Bq[0][0] * R[1][0] + Bq[0][1] * R[1][1] + Bq[0][2] * R[1][2];
    M[5] = Bq[0][0] * R[2][0] + Bq[0][1] * R[2][1] + Bq[0][2] * R[2][2];
    M[6] = Bq[1][0] * R[1][0] + Bq[1][1] * R[1][1] + Bq[1][2] * R[1][2];
    M[7] = Bq[1][0] * R[2][0] + Bq[1][1] * R[2][1] + Bq[1][2] * R[2][2];
    M[8] = Bq[2][0] * R[2][0] + Bq[2][1] * R[2][1] + Bq[2][2] * R[2][2];
}

__device__ inline float wredf(float v) {
    for (int off = 32; off > 0; off >>= 1) v += __shfl_xor(v, off);
    return v;
}
__device__ inline double wredd(double v) {
    for (int off = 32; off > 0; off >>= 1) v += __shfl_xor(v, off);
    return v;
}

// ====== main kernel: grid-stride atom loop; COOP adds grid-sync + final reduce ======
template <bool COOP>
__global__ void __launch_bounds__(256, 2)
k_all(const float* __restrict__ coords, const float* __restrict__ box,
      double* __restrict__ wsd, float* __restrict__ out, int N) {
    __shared__ float4 sh_list[MAXN];      // per-wave compacted (dr, b) segments
    __shared__ float  sh_muQ[MAXN * 9];   // multipoles of survivors, slot-parallel
    __shared__ double sh_red[NWAVE * 5];

    int tid = threadIdx.x;
    int w = tid >> 6, lane = tid & 63;
    float bx[3][3], bi[3][3];
    load_boxf(box, bx, bi);

    for (int a = blockIdx.x; a < N; a += gridDim.x) {
        int wa = a / 3;
        int ta = (a - wa * 3) ? 1 : 0;
        f3 ca = getcf(coords, a);

        // own-atom frame + multipoles (uniform across block)
        float Ra[3][3]; int tt0;
        calc_frame(coords, bx, bi, a, Ra, &tt0);
        float MA[9];
        rot_muQ(Ra, ta, MA);
        f3 mua = {MA[0], MA[1], MA[2]};
        float Qaxx = MA[3], Qaxy = MA[4], Qaxz = MA[5], Qayy = MA[6], Qayz = MA[7], Qazz = MA[8];

        // ---- phase 1: per-wave cutoff compaction into own LDS segment ----
        int chunks = (N + 64 * NWAVE - 1) / (64 * NWAVE);
        int seg = chunks * 64;
        int base = w * seg;
        int cnt = 0;
        for (int k = 0; k < chunks; ++k) {
            int b = base + k * 64 + lane;
            bool pred = false;
            f3 dr = {0.f, 0.f, 0.f};
            if (b < N) {
                int wb = b / 3;
                dr = pbcf(getcf(coords, b) - ca, bx, bi);
                pred = (wb != wa) && (dotf(dr, dr) < RCUT2F);
            }
            unsigned long long mask = __ballot(pred);
            int pref = __popcll(mask & ((1ull << lane) - 1ull));
            if (pred) sh_list[base + cnt + pref] = make_float4(dr.x, dr.y, dr.z, __int_as_float(b));
            cnt += __popcll(mask);
        }

        // ---- phase 1b: multipoles for SURVIVORS only (wave-local slots) ----
        for (int i = lane; i < cnt; i += 64) {
            int b = __float_as_int(sh_list[base + i].w);
            float Rb[3][3]; int tb;
            calc_frame(coords, bx, bi, b, Rb, &tb);
            float MB[9];
            rot_muQ(Rb, tb, MB);
            float* dst = &sh_muQ[(base + i) * 9];
            for (int k = 0; k < 9; ++k) dst[k] = MB[k];
        }

        // ---- type-pair dual constants ----
        float Zi = TF(Zc_, ta), qi = TF(QSH_, ta), qti = Zi + qi;
        float beli = TF(B_EL_, ta);
        float belj0 = (float)B_EL_[0], belj1 = (float)B_EL_[1];
        float bije0 = sqrtf(beli * belj0), bije1 = sqrtf(beli * belj1);
        float qtj0 = (float)(Zc_[0] + QSH_[0]), qtj1 = (float)(Zc_[1] + QSH_[1]);
        float Ziqj0 = Zi * (float)QSH_[0], Ziqj1 = Zi * (float)QSH_[1];
        float Zjqi0 = (float)Zc_[0] * qi, Zjqi1 = (float)Zc_[1] * qi;
        float qiqj0 = qi * (float)QSH_[0], qiqj1 = qi * (float)QSH_[1];
        float qq0 = qti * qtj0, qq1 = qti * qtj1;
        float sacci = TF(SACC_, ta);
        float saccj0 = (float)SACC_[0], saccj1 = (float)SACC_[1];
        float sdi = TF(SDON_, ta), kddi = TF(KD_DO_, ta), kqdi = TF(KQ_DO_, ta);
        float sdj0 = (float)SDON_[0], sdj1 = (float)SDON_[1];
        float kddj0 = (float)KD_DO_[0], kddj1 = (float)KD_DO_[1];
        float kqdj0 = (float)KQ_DO_[0], kqdj1 = (float)KQ_DO_[1];
        float bctt = TF(B_CT_, ta);
        float bijct0 = sqrtf(bctt * (float)B_CT_[0]), bijct1 = sqrtf(bctt * (float)B_CT_[1]);
        float inve0 = (ta == 0) ? 1e-15f : (float)(1.0 / EPS_OFF);
        float inve1 = (ta == 1) ? 1e-15f : (float)(1.0 / EPS_OFF);
        float spi = TF(SPA_, ta), kdpi = TF(KD_PA_, ta), kqpi = TF(KQ_PA_, ta);
        float spj0 = (float)SPA_[0], spj1 = (float)SPA_[1];
        float kdpj0 = (float)KD_PA_[0], kdpj1 = (float)KD_PA_[1];
        float kqpj0 = (float)KQ_PA_[0], kqpj1 = (float)KQ_PA_[1];
        float bpat = TF(B_PA_, ta);
        float bijpa0 = sqrtf(bpat * (float)B_PA_[0]), bijpa1 = sqrtf(bpat * (float)B_PA_[1]);
        float bxpt = TF(B_XP_, ta);
        float bijxp0 = sqrtf(bxpt * (float)B_XP_[0]), bijxp1 = sqrtf(bxpt * (float)B_XP_[1]);
        float sxpi = TF(SXP_, ta);
        float cxp0 = sxpi * (float)SXP_[0], cxp1 = sxpi * (float)SXP_[1];
        float bdt = TF(B_D_, ta);
        float bijd0 = sqrtf(bdt * (float)B_D_[0]), bijd1 = sqrtf(bdt * (float)B_D_[1]);
        float c6t = TF(C6_, ta);
        float c60 = sqrtf(c6t * (float)C6_[0]), c61 = sqrtf(c6t * (float)C6_[1]);

        // ---- phase 2: dense pair loop over this wave's survivors (f32 accum) ----
        float e = 0.f, efx = 0.f, efy = 0.f, efz = 0.f, dqa = 0.f;
        for (int i = lane; i < cnt; i += 64) {
            float4 E4 = sh_list[base + i];
            f3 dr = {E4.x, E4.y, E4.z};
            int b = __float_as_int(E4.w);
            int wb = b / 3;
            int tb = (b - wb * 3) ? 1 : 0;
            float r2 = dotf(dr, dr);
            float invr = rsqrtf(r2);
            float r = r2 * invr;
            f3 nv = dr * invr;
            float invr2 = invr * invr, invr3 = invr2 * invr;

            const float* MB = &sh_muQ[(base + i) * 9];
            f3 mub = {MB[0], MB[1], MB[2]};
            float muin = dotf(mua, nv), mujn = dotf(mub, nv);
            float nQni = Qaxx * nv.x * nv.x + Qayy * nv.y * nv.y + Qazz * nv.z * nv.z +
                         2.f * (Qaxy * nv.x * nv.y + Qaxz * nv.x * nv.z + Qayz * nv.y * nv.z);
            float nQnj = MB[3] * nv.x * nv.x + MB[6] * nv.y * nv.y + MB[8] * nv.z * nv.z +
                         2.f * (MB[4] * nv.x * nv.y + MB[5] * nv.x * nv.z + MB[7] * nv.y * nv.z);

            // permanent electrostatics (e_qq rearranged: no large-term cancellation)
            float fdm = f1mf(S(bije) * r);
            float fd = 1.f + fdm;
            float ep = (S(qq) + S(Ziqj) * f1mf(S(belj) * r) + S(Zjqi) * f1mf(beli * r) +
                        S(qiqj) * fdm) * invr;
            ep += fd * (S(qtj) * muin - qti * mujn) * invr2;
            ep += fd * (dotf(mua, mub) - 3.f * muin * mujn) * invr3;
            ep += 3.f * fd * (qti * nQnj + S(qtj) * nQni) * invr3;

            // field at atom a
            float cc = -S(qtj) * invr2 + 3.f * mujn * invr3;
            efx += fd * (cc * nv.x - mub.x * invr3);
            efy += fd * (cc * nv.y - mub.y * invr3);
            efz += fd * (cc * nv.z - mub.z * invr3);

            // charge transfer
            float sdon_i = sdi + kddi * muin + kqdi * nQni;
            float sdon_j = S(sdj) - S(kddj) * mujn + S(kqdj) * nQnj;
            float sct_r = __expf(-S(bijct) * r) * invr;
            ep -= (sdon_i * S(saccj) + sdon_j * sacci) * sct_r;
            dqa += sdon_j * sacci * sct_r * S(inve);

            // Pauli repulsion
            float si = spi + kdpi * muin + kqpi * nQni;
            float sj = S(spj) - S(kdpj) * mujn + S(kqpj) * nQnj;
            ep += si * sj * __expf(-S(bijpa) * r) * invr;

            // exchange polarization
            ep -= S(cxp) * __expf(-S(bijxp) * r) * invr;

            // Tang-Toennies dispersion
            float u = S(bijd) * r;
            float poly = 1.f + u * (1.f + u * (0.5f + u * (0.16666667f + u * (4.1666667e-2f +
                         u * (8.3333333e-3f + u * 1.3888889e-3f)))));
            ep -= (1.f - __expf(-u) * poly) * S(c6) * invr3 * invr3;

            e += ep;
        }

        // ---- reduction: wave shuffle (f32), then cross-wave via LDS (f64) ----
        e = wredf(e); efx = wredf(efx); efy = wredf(efy); efz = wredf(efz); dqa = wredf(dqa);
        if (lane == 0) {
            sh_red[w * 5 + 0] = (double)e;
            sh_red[w * 5 + 1] = (double)efx;
            sh_red[w * 5 + 2] = (double)efy;
            sh_red[w * 5 + 3] = (double)efz;
            sh_red[w * 5 + 4] = (double)dqa;
        }
        __syncthreads();

        if (tid == 0) {
            double se = 0, sx = 0, sy = 0, sz = 0, sq = 0;
            for (int k = 0; k < NWAVE; ++k) {
                se += sh_red[k * 5 + 0];
                sx += sh_red[k * 5 + 1];
                sy += sh_red[k * 5 + 2];
                sz += sh_red[k * 5 + 3];
                sq += sh_red[k * 5 + 4];
            }
            double tot = 0.5 * se;
            // polarization: -1/2 E.alpha.E, alpha = Ra diag Ra^T  -> v = Ra^T E
            double v0 = (double)Ra[0][0] * sx + (double)Ra[1][0] * sy + (double)Ra[2][0] * sz;
            double v1 = (double)Ra[0][1] * sx + (double)Ra[1][1] * sy + (double)Ra[2][1] * sz;
            double v2 = (double)Ra[0][2] * sx + (double)Ra[1][2] * sy + (double)Ra[2][2] * sz;
            tot -= 0.5 * ((ta ? AD_[1][0] : AD_[0][0]) * v0 * v0 +
                          (ta ? AD_[1][1] : AD_[0][1]) * v1 * v1 +
                          (ta ? AD_[1][2] : AD_[0][2]) * v2 * v2);
            // indirect charge transfer
            tot += 0.5 * (ta ? ETA_[1] : ETA_[0]) * sq * sq;

            // bonded terms: O-blocks handle their water (f64)
            if (ta == 0) {
                double bxd[3][3], bid[3][3];
                load_boxd(box, bxd, bid);
                d3 cO = getcd(coords, 3 * wa);
                d3 b1 = pbcd(subd(getcd(coords, 3 * wa + 1), cO), bxd, bid);
                d3 b2 = pbcd(subd(getcd(coords, 3 * wa + 2), cO), bxd, bid);
                double l1 = sqrt(dotd(b1, b1)), l2 = sqrt(dotd(b2, b2));
                double beta = sqrt(K_B / (2.0 * D_M));
                double x1 = 1.0 - exp(-beta * (l1 - B_EQ));
                double x2 = 1.0 - exp(-beta * (l2 - B_EQ));
                tot += D_M * (x1 * x1 + x2 * x2);
                tot += K_BB * (l1 - B_EQ) * (l2 - B_EQ);
                double cang = dotd(b1, b2) / (l1 * l2);
                cang = fmin(fmax(cang, -1.0 + 1e-7), 1.0 - 1e-7);
                double th = acos(cang);
                double cte = cos(TH_EQ);
                tot += 0.5 * K_TH * (cang - cte) * (cang - cte);
                tot += K_BA * ((l1 - B_EQ) + (l2 - B_EQ)) * (th - TH_EQ);
            }
            wsd[a] = tot;   // deterministic per-atom partial
        }
        __syncthreads();   // protect sh_red / LDS reuse on next atom iteration
    }

    if constexpr (COOP) {
        __threadfence();
        cg::this_grid().sync();
        if (blockIdx.x == 0) {
            double v = 0.0;
            for (int i = tid; i < N; i += 256) v += wsd[i];
            v = wredd(v);
            __shared__ double s2[4];
            if (lane == 0) s2[w] = v;
            __syncthreads();
            if (tid == 0) out[0] = (float)(s2[0] + s2[1] + s2[2] + s2[3]);
        }
    }
}

// =============== fallback kernel 2: deterministic final reduce ===============
__global__ void __launch_bounds__(256) k_final(const double* __restrict__ wsd,
                                               float* __restrict__ out, int N) {
    int tid = threadIdx.x;
    int w = tid >> 6, lane = tid & 63;
    double v = 0.0;
    for (int i = tid; i < N; i += 256) v += wsd[i];
    v = wredd(v);
    __shared__ double s[4];
    if (lane == 0) s[w] = v;
    __syncthreads();
    if (tid == 0) out[0] = (float)(s[0] + s[1] + s[2] + s[3]);
}

extern "C" void kernel_launch(void* const* d_in, const int* in_sizes, int n_in,
                              void* d_out, int out_size, void* d_ws, size_t ws_size,
                              hipStream_t stream) {
    const float* coords = (const float*)d_in[0];
    const float* box    = (const float*)d_in[1];
    int N = in_sizes[0] / 3;  // atoms (768)
    double* wsd = (double*)d_ws;
    float* out = (float*)d_out;

    // cooperative path: grid = ceil(N/2) blocks (<= runtime coop limit with margin)
    int nblk = (N + 1) / 2;
    void* args[] = {(void*)&coords, (void*)&box, (void*)&wsd, (void*)&out, (void*)&N};
    hipError_t err = hipLaunchCooperativeKernel((const void*)k_all<true>, dim3(nblk),
                                                dim3(256), args, 0, stream);
    if (err != hipSuccess) {
        // fallback: proven two-node path (block per atom + tiny reduce)
        k_all<false><<<N, 256, 0, stream>>>(coords, box, wsd, out, N);
        k_final<<<1, 256, 0, stream>>>(wsd, out, N);
    }
}

// Round 8
// 24.920 us; speedup vs baseline: 3.4581x; 3.4581x over previous
//
#include <hip/hip_runtime.h>
#include <math.h>

// ---------------- constants (atomic units) ----------------
constexpr double B2A   = 0.52917721067;
constexpr double H2KJ  = 2625.499638;
constexpr float  RCUT2F = (float)((10.0 / B2A) * (10.0 / B2A));

constexpr double Zc_[2]   = {3.61565, 0.93619};
constexpr double MONO_[2] = {-0.390896, 0.195448};
constexpr double QSH_[2]  = {MONO_[0] - Zc_[0], MONO_[1] - Zc_[1]};
constexpr double DIPO_[2][3] = {{0.0, 0.0, -0.094298},
                                {0.0910288, 0.0, -0.207851}};
constexpr double QS_[2][5] = {{-0.330685, 0.0, 0.0, 0.869923, 0.0},
                              {-0.0739388, 0.0929482, 0.0, 0.00532425, 0.0}};
constexpr double B_EL_[2]  = {2.13358, 2.33322};
constexpr double B_PA_[2]  = {2.1975, 1.96474};
constexpr double SPA_[2]   = {6.50923, 0.527804};
constexpr double KD_PA_[2] = {-5.61925, -0.515584};
constexpr double KQ_PA_[2] = {-1.56567, -0.440164};
constexpr double C6_[2]    = {35.8289, 1.98954};
constexpr double B_D_[2]   = {1.84302, 1.30993};
constexpr double AD_[2][3] = {{4.45992, 6.07259, 4.55391},
                              {2.22001, 1.66835, 0.183855}};
constexpr double ETA_[2]   = {6.18699e-06 * 2.0, 0.561535 * 2.0};
constexpr double B_XP_[2]  = {2.73582, 2.04028};
constexpr double SXP_[2]   = {1.26592, 0.200089};
constexpr double B_CT_[2]  = {1.89485, 2.36763};
constexpr double SACC_[2]  = {-0.67857, 1.36735};
constexpr double SDON_[2]  = {0.757752, 0.00888982};
constexpr double KD_DO_[2] = {-0.512036, -0.0511668};
constexpr double KQ_DO_[2] = {-0.208186, 0.0568152};
constexpr double EPS_OFF = 0.380979;

constexpr double D_M   = 524.265 / H2KJ;
constexpr double K_B   = 5098.15 / H2KJ * B2A * B2A;
constexpr double B_EQ  = 0.958413 / B2A;
constexpr double K_BB  = -61.1423 / H2KJ * B2A * B2A;
constexpr double K_BA  = -159.886 / H2KJ * B2A;
constexpr double TH_EQ = 104.4234 * M_PI / 180.0;
constexpr double K_TH  = 452.183 / H2KJ;
constexpr double SQ32  = 0.86602540378443864676;

// local-frame quadrupole (traceless Cartesian), /3 folded; q21s=q22s=0 -> only xx,yy,zz,xz
constexpr double QLXX_[2] = {(-0.5 * QS_[0][0] + SQ32 * QS_[0][3]) / 3.0,
                             (-0.5 * QS_[1][0] + SQ32 * QS_[1][3]) / 3.0};
constexpr double QLYY_[2] = {(-0.5 * QS_[0][0] - SQ32 * QS_[0][3]) / 3.0,
                             (-0.5 * QS_[1][0] - SQ32 * QS_[1][3]) / 3.0};
constexpr double QLZZ_[2] = {QS_[0][0] / 3.0, QS_[1][0] / 3.0};
constexpr double QLXZ_[2] = {SQ32 * QS_[0][1] / 3.0, SQ32 * QS_[1][1] / 3.0};
constexpr double DIP0_[2] = {DIPO_[0][0], DIPO_[1][0]};
constexpr double DIP2_[2] = {DIPO_[0][2], DIPO_[1][2]};

#define NWAVE 3           // waves per block (192 threads)
#define SEG   128         // sh_list slots per wave (2 chunks of 64)
#define TF(A, t) ((t) ? (float)A[1] : (float)A[0])
#define S(x) (tb ? x##1 : x##0)

// ---------------- f32 vec helpers ----------------
struct f3 { float x, y, z; };
__device__ inline f3 operator-(f3 a, f3 b) { return {a.x - b.x, a.y - b.y, a.z - b.z}; }
__device__ inline f3 operator+(f3 a, f3 b) { return {a.x + b.x, a.y + b.y, a.z + b.z}; }
__device__ inline f3 operator*(f3 a, float s) { return {a.x * s, a.y * s, a.z * s}; }
__device__ inline float dotf(f3 a, f3 b) { return a.x * b.x + a.y * b.y + a.z * b.z; }
__device__ inline f3 crossf(f3 a, f3 b) {
    return {a.y * b.z - a.z * b.y, a.z * b.x - a.x * b.z, a.x * b.y - a.y * b.x};
}
__device__ inline f3 normf(f3 a) { float s = rsqrtf(dotf(a, a)); return a * s; }
__device__ inline f3 getcf(const float* c, int i) {
    return {c[3 * i], c[3 * i + 1], c[3 * i + 2]};
}
__device__ inline void load_boxf(const float* box, float bx[3][3], float bi[3][3]) {
    for (int i = 0; i < 3; ++i)
        for (int j = 0; j < 3; ++j) bx[i][j] = box[i * 3 + j];
    float a = bx[0][0], b = bx[0][1], c = bx[0][2];
    float d = bx[1][0], e = bx[1][1], f = bx[1][2];
    float g = bx[2][0], h = bx[2][1], i2 = bx[2][2];
    float A =  (e * i2 - f * h), B = -(d * i2 - f * g), C =  (d * h - e * g);
    float D = -(b * i2 - c * h), E =  (a * i2 - c * g), F = -(a * h - b * g);
    float G =  (b * f - c * e),  H = -(a * f - c * d),  I =  (a * e - b * d);
    float s = 1.0f / (a * A + b * B + c * C);
    bi[0][0] = A * s; bi[0][1] = D * s; bi[0][2] = G * s;
    bi[1][0] = B * s; bi[1][1] = E * s; bi[1][2] = H * s;
    bi[2][0] = C * s; bi[2][1] = F * s; bi[2][2] = I * s;
}
__device__ inline f3 pbcf(f3 d, const float bx[3][3], const float bi[3][3]) {
    float s0 = rintf(d.x * bi[0][0] + d.y * bi[1][0] + d.z * bi[2][0]);
    float s1 = rintf(d.x * bi[0][1] + d.y * bi[1][1] + d.z * bi[2][1]);
    float s2 = rintf(d.x * bi[0][2] + d.y * bi[1][2] + d.z * bi[2][2]);
    d.x -= s0 * bx[0][0] + s1 * bx[1][0] + s2 * bx[2][0];
    d.y -= s0 * bx[0][1] + s1 * bx[1][1] + s2 * bx[2][1];
    d.z -= s0 * bx[0][2] + s1 * bx[1][2] + s2 * bx[2][2];
    return d;
}
__device__ inline float f1mf(float u) { return -__expf(-u) * (1.0f + 0.5f * u); }  // f1 - 1

// ---------------- f64 helpers (bonded terms only) ----------------
struct d3 { double x, y, z; };
__device__ inline d3 subd(d3 a, d3 b) { return {a.x - b.x, a.y - b.y, a.z - b.z}; }
__device__ inline double dotd(d3 a, d3 b) { return a.x * b.x + a.y * b.y + a.z * b.z; }
__device__ inline d3 getcd(const float* c, int i) {
    return {(double)c[3 * i], (double)c[3 * i + 1], (double)c[3 * i + 2]};
}
__device__ inline void load_boxd(const float* box, double bx[3][3], double bi[3][3]) {
    for (int i = 0; i < 3; ++i)
        for (int j = 0; j < 3; ++j) bx[i][j] = (double)box[i * 3 + j];
    double a = bx[0][0], b = bx[0][1], c = bx[0][2];
    double d = bx[1][0], e = bx[1][1], f = bx[1][2];
    double g = bx[2][0], h = bx[2][1], i2 = bx[2][2];
    double A =  (e * i2 - f * h), B = -(d * i2 - f * g), C =  (d * h - e * g);
    double D = -(b * i2 - c * h), E =  (a * i2 - c * g), F = -(a * h - b * g);
    double G =  (b * f - c * e),  H = -(a * f - c * d),  I =  (a * e - b * d);
    double s = 1.0 / (a * A + b * B + c * C);
    bi[0][0] = A * s; bi[0][1] = D * s; bi[0][2] = G * s;
    bi[1][0] = B * s; bi[1][1] = E * s; bi[1][2] = H * s;
    bi[2][0] = C * s; bi[2][1] = F * s; bi[2][2] = I * s;
}
__device__ inline d3 pbcd(d3 d, const double bx[3][3], const double bi[3][3]) {
    double s0 = rint(d.x * bi[0][0] + d.y * bi[1][0] + d.z * bi[2][0]);
    double s1 = rint(d.x * bi[0][1] + d.y * bi[1][1] + d.z * bi[2][1]);
    double s2 = rint(d.x * bi[0][2] + d.y * bi[1][2] + d.z * bi[2][2]);
    d.x -= s0 * bx[0][0] + s1 * bx[1][0] + s2 * bx[2][0];
    d.y -= s0 * bx[0][1] + s1 * bx[1][1] + s2 * bx[2][1];
    d.z -= s0 * bx[0][2] + s1 * bx[1][2] + s2 * bx[2][2];
    return d;
}

// ---------------- frame (local axes) ----------------
__device__ inline void calc_frame(const float* coords, const float bx[3][3],
                                  const float bi[3][3], int n, float R[3][3], int* tt) {
    int w = n / 3, m = n - w * 3, o = w * 3;
    int zat = (m == 0) ? n + 1 : o;
    int xat = (m == 0) ? n + 2 : ((m == 1) ? n + 1 : n - 1);
    f3 cn = getcf(coords, n);
    f3 uz = normf(pbcf(getcf(coords, zat) - cn, bx, bi));
    f3 ux = normf(pbcf(getcf(coords, xat) - cn, bx, bi));
    f3 zax = (m == 0) ? normf(uz + ux) : uz;
    f3 xax = normf(ux - zax * dotf(ux, zax));
    f3 yax = crossf(zax, xax);
    R[0][0] = xax.x; R[0][1] = yax.x; R[0][2] = zax.x;
    R[1][0] = xax.y; R[1][1] = yax.y; R[1][2] = zax.y;
    R[2][0] = xax.z; R[2][1] = yax.z; R[2][2] = zax.z;
    *tt = (m == 0) ? 0 : 1;
}

// rotated multipoles: M = [mu0,mu1,mu2, Qxx,Qxy,Qxz,Qyy,Qyz,Qzz]
__device__ inline void rot_muQ(const float R[3][3], int t, float M[9]) {
    float d0 = TF(DIP0_, t), d2 = TF(DIP2_, t);
    M[0] = R[0][0] * d0 + R[0][2] * d2;
    M[1] = R[1][0] * d0 + R[1][2] * d2;
    M[2] = R[2][0] * d0 + R[2][2] * d2;
    float qlxx = TF(QLXX_, t), qlyy = TF(QLYY_, t), qlzz = TF(QLZZ_, t), qlxz = TF(QLXZ_, t);
    float Bq[3][3];
    for (int p = 0; p < 3; ++p) {
        Bq[p][0] = R[p][0] * qlxx + R[p][2] * qlxz;
        Bq[p][1] = R[p][1] * qlyy;
        Bq[p][2] = R[p][0] * qlxz + R[p][2] * qlzz;
    }
    M[3] = Bq[0][0] * R[0][0] + Bq[0][1] * R[0][1] + Bq[0][2] * R[0][2];
    M[4] = Bq[0][0] * R[1][0] + Bq[0][1] * R[1][1] + Bq[0][2] * R[1][2];
    M[5] = Bq[0][0] * R[2][0] + Bq[0][1] * R[2][1] + Bq[0][2] * R[2][2];
    M[6] = Bq[1][0] * R[1][0] + Bq[1][1] * R[1][1] + Bq[1][2] * R[1][2];
    M[7] = Bq[1][0] * R[2][0] + Bq[1][1] * R[2][1] + Bq[1][2] * R[2][2];
    M[8] = Bq[2][0] * R[2][0] + Bq[2][1] * R[2][1] + Bq[2][2] * R[2][2];
}

__device__ inline float wredf(float v) {
    for (int off = 32; off > 0; off >>= 1) v += __shfl_xor(v, off);
    return v;
}

// ws layout (doubles): EP[2N] | EF[2N*3] | DQ[2N]  (indexed by bid = 2a+h)
// =============== kernel 1: 2 blocks per atom, 192 threads (3 waves) ===============
__global__ void __launch_bounds__(192, 4)
k_main(const float* __restrict__ coords, const float* __restrict__ box,
       double* __restrict__ wsd, int N) {
    __shared__ float4 sh_list[NWAVE * SEG];
    __shared__ float  sh_muQ[NWAVE * SEG * 9];
    __shared__ double sh_red[NWAVE * 5];

    int bid = blockIdx.x;
    int a = bid >> 1, h = bid & 1;        // atom, half
    int tid = threadIdx.x;
    int w = tid >> 6, lane = tid & 63;
    float bx[3][3], bi[3][3];
    load_boxf(box, bx, bi);

    int wa = a / 3;
    int ta = (a - wa * 3) ? 1 : 0;
    f3 ca = getcf(coords, a);

    // own-atom frame + multipoles
    float Ra[3][3]; int tt0;
    calc_frame(coords, bx, bi, a, Ra, &tt0);
    float MA[9];
    rot_muQ(Ra, ta, MA);
    f3 mua = {MA[0], MA[1], MA[2]};
    float Qaxx = MA[3], Qaxy = MA[4], Qaxz = MA[5], Qayy = MA[6], Qayz = MA[7], Qazz = MA[8];

    // ---- phase 1: compaction. Block h owns chunks {h, h+2, ...}; wave w takes the
    //      j=2w and j=2w+1 of those 6 -> candidates c = h + 2j.
    int nch = (N + 63) >> 6;   // 12 for N=768
    int base = w * SEG;
    int cnt = 0;
    for (int j = 2 * w; j <= 2 * w + 1; ++j) {
        int c = h + 2 * j;
        if (c >= nch) break;
        int b = c * 64 + lane;
        bool pred = false;
        f3 dr = {0.f, 0.f, 0.f};
        if (b < N) {
            int wb = b / 3;
            dr = pbcf(getcf(coords, b) - ca, bx, bi);
            pred = (wb != wa) && (dotf(dr, dr) < RCUT2F);
        }
        unsigned long long mask = __ballot(pred);
        int pref = __popcll(mask & ((1ull << lane) - 1ull));
        if (pred) sh_list[base + cnt + pref] = make_float4(dr.x, dr.y, dr.z, __int_as_float(b));
        cnt += __popcll(mask);
    }

    // ---- phase 1b: multipoles for survivors only (wave-local slots) ----
    for (int i = lane; i < cnt; i += 64) {
        int b = __float_as_int(sh_list[base + i].w);
        float Rb[3][3]; int tb;
        calc_frame(coords, bx, bi, b, Rb, &tb);
        float MB[9];
        rot_muQ(Rb, tb, MB);
        float* dst = &sh_muQ[(base + i) * 9];
        for (int k = 0; k < 9; ++k) dst[k] = MB[k];
    }

    // ---- type-pair dual constants ----
    float Zi = TF(Zc_, ta), qi = TF(QSH_, ta), qti = Zi + qi;
    float beli = TF(B_EL_, ta);
    float belj0 = (float)B_EL_[0], belj1 = (float)B_EL_[1];
    float bije0 = sqrtf(beli * belj0), bije1 = sqrtf(beli * belj1);
    float qtj0 = (float)(Zc_[0] + QSH_[0]), qtj1 = (float)(Zc_[1] + QSH_[1]);
    float Ziqj0 = Zi * (float)QSH_[0], Ziqj1 = Zi * (float)QSH_[1];
    float Zjqi0 = (float)Zc_[0] * qi, Zjqi1 = (float)Zc_[1] * qi;
    float qiqj0 = qi * (float)QSH_[0], qiqj1 = qi * (float)QSH_[1];
    float qq0 = qti * qtj0, qq1 = qti * qtj1;
    float sacci = TF(SACC_, ta);
    float saccj0 = (float)SACC_[0], saccj1 = (float)SACC_[1];
    float sdi = TF(SDON_, ta), kddi = TF(KD_DO_, ta), kqdi = TF(KQ_DO_, ta);
    float sdj0 = (float)SDON_[0], sdj1 = (float)SDON_[1];
    float kddj0 = (float)KD_DO_[0], kddj1 = (float)KD_DO_[1];
    float kqdj0 = (float)KQ_DO_[0], kqdj1 = (float)KQ_DO_[1];
    float bctt = TF(B_CT_, ta);
    float bijct0 = sqrtf(bctt * (float)B_CT_[0]), bijct1 = sqrtf(bctt * (float)B_CT_[1]);
    float inve0 = (ta == 0) ? 1e-15f : (float)(1.0 / EPS_OFF);
    float inve1 = (ta == 1) ? 1e-15f : (float)(1.0 / EPS_OFF);
    float spi = TF(SPA_, ta), kdpi = TF(KD_PA_, ta), kqpi = TF(KQ_PA_, ta);
    float spj0 = (float)SPA_[0], spj1 = (float)SPA_[1];
    float kdpj0 = (float)KD_PA_[0], kdpj1 = (float)KD_PA_[1];
    float kqpj0 = (float)KQ_PA_[0], kqpj1 = (float)KQ_PA_[1];
    float bpat = TF(B_PA_, ta);
    float bijpa0 = sqrtf(bpat * (float)B_PA_[0]), bijpa1 = sqrtf(bpat * (float)B_PA_[1]);
    float bxpt = TF(B_XP_, ta);
    float bijxp0 = sqrtf(bxpt * (float)B_XP_[0]), bijxp1 = sqrtf(bxpt * (float)B_XP_[1]);
    float sxpi = TF(SXP_, ta);
    float cxp0 = sxpi * (float)SXP_[0], cxp1 = sxpi * (float)SXP_[1];
    float bdt = TF(B_D_, ta);
    float bijd0 = sqrtf(bdt * (float)B_D_[0]), bijd1 = sqrtf(bdt * (float)B_D_[1]);
    float c6t = TF(C6_, ta);
    float c60 = sqrtf(c6t * (float)C6_[0]), c61 = sqrtf(c6t * (float)C6_[1]);

    // ---- phase 2: dense pair loop (f32 accum) ----
    float e = 0.f, efx = 0.f, efy = 0.f, efz = 0.f, dqa = 0.f;
    for (int i = lane; i < cnt; i += 64) {
        float4 E4 = sh_list[base + i];
        f3 dr = {E4.x, E4.y, E4.z};
        int b = __float_as_int(E4.w);
        int wb = b / 3;
        int tb = (b - wb * 3) ? 1 : 0;
        float r2 = dotf(dr, dr);
        float invr = rsqrtf(r2);
        float r = r2 * invr;
        f3 nv = dr * invr;
        float invr2 = invr * invr, invr3 = invr2 * invr;

        const float* MB = &sh_muQ[(base + i) * 9];
        f3 mub = {MB[0], MB[1], MB[2]};
        float muin = dotf(mua, nv), mujn = dotf(mub, nv);
        float nQni = Qaxx * nv.x * nv.x + Qayy * nv.y * nv.y + Qazz * nv.z * nv.z +
                     2.f * (Qaxy * nv.x * nv.y + Qaxz * nv.x * nv.z + Qayz * nv.y * nv.z);
        float nQnj = MB[3] * nv.x * nv.x + MB[6] * nv.y * nv.y + MB[8] * nv.z * nv.z +
                     2.f * (MB[4] * nv.x * nv.y + MB[5] * nv.x * nv.z + MB[7] * nv.y * nv.z);

        // permanent electrostatics (e_qq rearranged: no large-term cancellation)
        float fdm = f1mf(S(bije) * r);
        float fd = 1.f + fdm;
        float ep = (S(qq) + S(Ziqj) * f1mf(S(belj) * r) + S(Zjqi) * f1mf(beli * r) +
                    S(qiqj) * fdm) * invr;
        ep += fd * (S(qtj) * muin - qti * mujn) * invr2;
        ep += fd * (dotf(mua, mub) - 3.f * muin * mujn) * invr3;
        ep += 3.f * fd * (qti * nQnj + S(qtj) * nQni) * invr3;

        // field at atom a
        float cc = -S(qtj) * invr2 + 3.f * mujn * invr3;
        efx += fd * (cc * nv.x - mub.x * invr3);
        efy += fd * (cc * nv.y - mub.y * invr3);
        efz += fd * (cc * nv.z - mub.z * invr3);

        // charge transfer
        float sdon_i = sdi + kddi * muin + kqdi * nQni;
        float sdon_j = S(sdj) - S(kddj) * mujn + S(kqdj) * nQnj;
        float sct_r = __expf(-S(bijct) * r) * invr;
        ep -= (sdon_i * S(saccj) + sdon_j * sacci) * sct_r;
        dqa += sdon_j * sacci * sct_r * S(inve);

        // Pauli repulsion
        float si = spi + kdpi * muin + kqpi * nQni;
        float sj = S(spj) - S(kdpj) * mujn + S(kqpj) * nQnj;
        ep += si * sj * __expf(-S(bijpa) * r) * invr;

        // exchange polarization
        ep -= S(cxp) * __expf(-S(bijxp) * r) * invr;

        // Tang-Toennies dispersion
        float u = S(bijd) * r;
        float poly = 1.f + u * (1.f + u * (0.5f + u * (0.16666667f + u * (4.1666667e-2f +
                     u * (8.3333333e-3f + u * 1.3888889e-3f)))));
        ep -= (1.f - __expf(-u) * poly) * S(c6) * invr3 * invr3;

        e += ep;
    }

    // ---- reduction: wave shuffle (f32), cross-wave via LDS (f64) ----
    e = wredf(e); efx = wredf(efx); efy = wredf(efy); efz = wredf(efz); dqa = wredf(dqa);
    if (lane == 0) {
        sh_red[w * 5 + 0] = (double)e;
        sh_red[w * 5 + 1] = (double)efx;
        sh_red[w * 5 + 2] = (double)efy;
        sh_red[w * 5 + 3] = (double)efz;
        sh_red[w * 5 + 4] = (double)dqa;
    }
    __syncthreads();

    if (tid == 0) {
        double se = 0, sx = 0, sy = 0, sz = 0, sq = 0;
        for (int k = 0; k < NWAVE; ++k) {
            se += sh_red[k * 5 + 0];
            sx += sh_red[k * 5 + 1];
            sy += sh_red[k * 5 + 2];
            sz += sh_red[k * 5 + 3];
            sq += sh_red[k * 5 + 4];
        }
        wsd[bid] = 0.5 * se;                      // EP
        double* EF = wsd + 2 * N + bid * 3;       // EF
        EF[0] = sx; EF[1] = sy; EF[2] = sz;
        wsd[8 * N + bid] = sq;                    // DQ
    }
}

// =============== kernel 2: combine halves + pol + CT-ind + bonded + reduce ========
__global__ void __launch_bounds__(256)
k_final(const float* __restrict__ coords, const float* __restrict__ box,
        const double* __restrict__ wsd, float* __restrict__ out, int N) {
    int tid = threadIdx.x;
    float bx[3][3], bi[3][3];
    load_boxf(box, bx, bi);
    double bxd[3][3], bid_[3][3];
    load_boxd(box, bxd, bid_);

    const double* EP = wsd;
    const double* EF = wsd + 2 * N;
    const double* DQ = wsd + 8 * N;

    double e = 0.0;
    for (int i = tid; i < N; i += 256) {
        e += EP[2 * i] + EP[2 * i + 1];
        double E0 = EF[(2 * i) * 3 + 0] + EF[(2 * i + 1) * 3 + 0];
        double E1 = EF[(2 * i) * 3 + 1] + EF[(2 * i + 1) * 3 + 1];
        double E2 = EF[(2 * i) * 3 + 2] + EF[(2 * i + 1) * 3 + 2];
        float Ra[3][3]; int t;
        calc_frame(coords, bx, bi, i, Ra, &t);
        // polarization: alpha = Ra diag Ra^T -> v = Ra^T E
        double v0 = (double)Ra[0][0] * E0 + (double)Ra[1][0] * E1 + (double)Ra[2][0] * E2;
        double v1 = (double)Ra[0][1] * E0 + (double)Ra[1][1] * E1 + (double)Ra[2][1] * E2;
        double v2 = (double)Ra[0][2] * E0 + (double)Ra[1][2] * E1 + (double)Ra[2][2] * E2;
        e -= 0.5 * ((t ? AD_[1][0] : AD_[0][0]) * v0 * v0 +
                    (t ? AD_[1][1] : AD_[0][1]) * v1 * v1 +
                    (t ? AD_[1][2] : AD_[0][2]) * v2 * v2);
        double dq = DQ[2 * i] + DQ[2 * i + 1];
        e += 0.5 * (t ? ETA_[1] : ETA_[0]) * dq * dq;

        if ((i % 3) == 0) {   // bonded terms, one per water (f64)
            int w = i / 3;
            d3 cO = getcd(coords, 3 * w);
            d3 b1 = pbcd(subd(getcd(coords, 3 * w + 1), cO), bxd, bid_);
            d3 b2 = pbcd(subd(getcd(coords, 3 * w + 2), cO), bxd, bid_);
            double l1 = sqrt(dotd(b1, b1)), l2 = sqrt(dotd(b2, b2));
            double beta = sqrt(K_B / (2.0 * D_M));
            double x1 = 1.0 - exp(-beta * (l1 - B_EQ));
            double x2 = 1.0 - exp(-beta * (l2 - B_EQ));
            e += D_M * (x1 * x1 + x2 * x2);
            e += K_BB * (l1 - B_EQ) * (l2 - B_EQ);
            double cang = dotd(b1, b2) / (l1 * l2);
            cang = fmin(fmax(cang, -1.0 + 1e-7), 1.0 - 1e-7);
            double th = acos(cang);
            double cte = cos(TH_EQ);
            e += 0.5 * K_TH * (cang - cte) * (cang - cte);
            e += K_BA * ((l1 - B_EQ) + (l2 - B_EQ)) * (th - TH_EQ);
        }
    }

    __shared__ double sh[256];
    sh[tid] = e;
    __syncthreads();
    for (int s = 128; s > 0; s >>= 1) {
        if (tid < s) sh[tid] += sh[tid + s];
        __syncthreads();
    }
    if (tid == 0) out[0] = (float)sh[0];
}

extern "C" void kernel_launch(void* const* d_in, const int* in_sizes, int n_in,
                              void* d_out, int out_size, void* d_ws, size_t ws_size,
                              hipStream_t stream) {
    const float* coords = (const float*)d_in[0];
    const float* box    = (const float*)d_in[1];
    int N = in_sizes[0] / 3;  // atoms (768)
    double* wsd = (double*)d_ws;
    float* out = (float*)d_out;

    k_main<<<2 * N, 192, 0, stream>>>(coords, box, wsd, N);
    k_final<<<1, 256, 0, stream>>>(coords, box, wsd, out, N);
}

// Round 9
// 23.674 us; speedup vs baseline: 3.6401x; 1.0526x over previous
//
#include <hip/hip_runtime.h>
#include <math.h>

// ---------------- constants (atomic units) ----------------
constexpr double B2A   = 0.52917721067;
constexpr double H2KJ  = 2625.499638;
constexpr float  RCUT2F = (float)((10.0 / B2A) * (10.0 / B2A));

constexpr double Zc_[2]   = {3.61565, 0.93619};
constexpr double MONO_[2] = {-0.390896, 0.195448};
constexpr double QSH_[2]  = {MONO_[0] - Zc_[0], MONO_[1] - Zc_[1]};
constexpr double DIPO_[2][3] = {{0.0, 0.0, -0.094298},
                                {0.0910288, 0.0, -0.207851}};
constexpr double QS_[2][5] = {{-0.330685, 0.0, 0.0, 0.869923, 0.0},
                              {-0.0739388, 0.0929482, 0.0, 0.00532425, 0.0}};
constexpr double B_EL_[2]  = {2.13358, 2.33322};
constexpr double B_PA_[2]  = {2.1975, 1.96474};
constexpr double SPA_[2]   = {6.50923, 0.527804};
constexpr double KD_PA_[2] = {-5.61925, -0.515584};
constexpr double KQ_PA_[2] = {-1.56567, -0.440164};
constexpr double C6_[2]    = {35.8289, 1.98954};
constexpr double B_D_[2]   = {1.84302, 1.30993};
constexpr double AD_[2][3] = {{4.45992, 6.07259, 4.55391},
                              {2.22001, 1.66835, 0.183855}};
constexpr double ETA_[2]   = {6.18699e-06 * 2.0, 0.561535 * 2.0};
constexpr double B_XP_[2]  = {2.73582, 2.04028};
constexpr double SXP_[2]   = {1.26592, 0.200089};
constexpr double B_CT_[2]  = {1.89485, 2.36763};
constexpr double SACC_[2]  = {-0.67857, 1.36735};
constexpr double SDON_[2]  = {0.757752, 0.00888982};
constexpr double KD_DO_[2] = {-0.512036, -0.0511668};
constexpr double KQ_DO_[2] = {-0.208186, 0.0568152};
constexpr double EPS_OFF = 0.380979;

constexpr double D_M   = 524.265 / H2KJ;
constexpr double K_B   = 5098.15 / H2KJ * B2A * B2A;
constexpr double B_EQ  = 0.958413 / B2A;
constexpr double K_BB  = -61.1423 / H2KJ * B2A * B2A;
constexpr double K_BA  = -159.886 / H2KJ * B2A;
constexpr double TH_EQ = 104.4234 * M_PI / 180.0;
constexpr double K_TH  = 452.183 / H2KJ;
constexpr double SQ32  = 0.86602540378443864676;

// local-frame quadrupole (traceless Cartesian), /3 folded; q21s=q22s=0 -> only xx,yy,zz,xz
constexpr double QLXX_[2] = {(-0.5 * QS_[0][0] + SQ32 * QS_[0][3]) / 3.0,
                             (-0.5 * QS_[1][0] + SQ32 * QS_[1][3]) / 3.0};
constexpr double QLYY_[2] = {(-0.5 * QS_[0][0] - SQ32 * QS_[0][3]) / 3.0,
                             (-0.5 * QS_[1][0] - SQ32 * QS_[1][3]) / 3.0};
constexpr double QLZZ_[2] = {QS_[0][0] / 3.0, QS_[1][0] / 3.0};
constexpr double QLXZ_[2] = {SQ32 * QS_[0][1] / 3.0, SQ32 * QS_[1][1] / 3.0};
constexpr double DIP0_[2] = {DIPO_[0][0], DIPO_[1][0]};
constexpr double DIP2_[2] = {DIPO_[0][2], DIPO_[1][2]};

#define MAXN 768
#define NWAVE 4
#define MAGIC 0x5CA1AB1E
#define TF(A, t) ((t) ? (float)A[1] : (float)A[0])
#define S(x) (tb ? x##1 : x##0)

// ---------------- f32 vec helpers ----------------
struct f3 { float x, y, z; };
__device__ inline f3 operator-(f3 a, f3 b) { return {a.x - b.x, a.y - b.y, a.z - b.z}; }
__device__ inline f3 operator+(f3 a, f3 b) { return {a.x + b.x, a.y + b.y, a.z + b.z}; }
__device__ inline f3 operator*(f3 a, float s) { return {a.x * s, a.y * s, a.z * s}; }
__device__ inline float dotf(f3 a, f3 b) { return a.x * b.x + a.y * b.y + a.z * b.z; }
__device__ inline f3 crossf(f3 a, f3 b) {
    return {a.y * b.z - a.z * b.y, a.z * b.x - a.x * b.z, a.x * b.y - a.y * b.x};
}
__device__ inline f3 normf(f3 a) { float s = rsqrtf(dotf(a, a)); return a * s; }
__device__ inline f3 getcf(const float* c, int i) {
    return {c[3 * i], c[3 * i + 1], c[3 * i + 2]};
}
__device__ inline void load_boxf(const float* box, float bx[3][3], float bi[3][3]) {
    for (int i = 0; i < 3; ++i)
        for (int j = 0; j < 3; ++j) bx[i][j] = box[i * 3 + j];
    float a = bx[0][0], b = bx[0][1], c = bx[0][2];
    float d = bx[1][0], e = bx[1][1], f = bx[1][2];
    float g = bx[2][0], h = bx[2][1], i2 = bx[2][2];
    float A =  (e * i2 - f * h), B = -(d * i2 - f * g), C =  (d * h - e * g);
    float D = -(b * i2 - c * h), E =  (a * i2 - c * g), F = -(a * h - b * g);
    float G =  (b * f - c * e),  H = -(a * f - c * d),  I =  (a * e - b * d);
    float s = 1.0f / (a * A + b * B + c * C);
    bi[0][0] = A * s; bi[0][1] = D * s; bi[0][2] = G * s;
    bi[1][0] = B * s; bi[1][1] = E * s; bi[1][2] = H * s;
    bi[2][0] = C * s; bi[2][1] = F * s; bi[2][2] = I * s;
}
__device__ inline f3 pbcf(f3 d, const float bx[3][3], const float bi[3][3]) {
    float s0 = rintf(d.x * bi[0][0] + d.y * bi[1][0] + d.z * bi[2][0]);
    float s1 = rintf(d.x * bi[0][1] + d.y * bi[1][1] + d.z * bi[2][1]);
    float s2 = rintf(d.x * bi[0][2] + d.y * bi[1][2] + d.z * bi[2][2]);
    d.x -= s0 * bx[0][0] + s1 * bx[1][0] + s2 * bx[2][0];
    d.y -= s0 * bx[0][1] + s1 * bx[1][1] + s2 * bx[2][1];
    d.z -= s0 * bx[0][2] + s1 * bx[1][2] + s2 * bx[2][2];
    return d;
}
__device__ inline float f1mf(float u) { return -__expf(-u) * (1.0f + 0.5f * u); }  // f1 - 1

// ---------------- f64 helpers (bonded terms only) ----------------
struct d3 { double x, y, z; };
__device__ inline d3 subd(d3 a, d3 b) { return {a.x - b.x, a.y - b.y, a.z - b.z}; }
__device__ inline double dotd(d3 a, d3 b) { return a.x * b.x + a.y * b.y + a.z * b.z; }
__device__ inline d3 getcd(const float* c, int i) {
    return {(double)c[3 * i], (double)c[3 * i + 1], (double)c[3 * i + 2]};
}
__device__ inline void load_boxd(const float* box, double bx[3][3], double bi[3][3]) {
    for (int i = 0; i < 3; ++i)
        for (int j = 0; j < 3; ++j) bx[i][j] = (double)box[i * 3 + j];
    double a = bx[0][0], b = bx[0][1], c = bx[0][2];
    double d = bx[1][0], e = bx[1][1], f = bx[1][2];
    double g = bx[2][0], h = bx[2][1], i2 = bx[2][2];
    double A =  (e * i2 - f * h), B = -(d * i2 - f * g), C =  (d * h - e * g);
    double D = -(b * i2 - c * h), E =  (a * i2 - c * g), F = -(a * h - b * g);
    double G =  (b * f - c * e),  H = -(a * f - c * d),  I =  (a * e - b * d);
    double s = 1.0 / (a * A + b * B + c * C);
    bi[0][0] = A * s; bi[0][1] = D * s; bi[0][2] = G * s;
    bi[1][0] = B * s; bi[1][1] = E * s; bi[1][2] = H * s;
    bi[2][0] = C * s; bi[2][1] = F * s; bi[2][2] = I * s;
}
__device__ inline d3 pbcd(d3 d, const double bx[3][3], const double bi[3][3]) {
    double s0 = rint(d.x * bi[0][0] + d.y * bi[1][0] + d.z * bi[2][0]);
    double s1 = rint(d.x * bi[0][1] + d.y * bi[1][1] + d.z * bi[2][1]);
    double s2 = rint(d.x * bi[0][2] + d.y * bi[1][2] + d.z * bi[2][2]);
    d.x -= s0 * bx[0][0] + s1 * bx[1][0] + s2 * bx[2][0];
    d.y -= s0 * bx[0][1] + s1 * bx[1][1] + s2 * bx[2][1];
    d.z -= s0 * bx[0][2] + s1 * bx[1][2] + s2 * bx[2][2];
    return d;
}

// ---------------- frame (local axes) ----------------
__device__ inline void calc_frame(const float* coords, const float bx[3][3],
                                  const float bi[3][3], int n, float R[3][3], int* tt) {
    int w = n / 3, m = n - w * 3, o = w * 3;
    int zat = (m == 0) ? n + 1 : o;
    int xat = (m == 0) ? n + 2 : ((m == 1) ? n + 1 : n - 1);
    f3 cn = getcf(coords, n);
    f3 uz = normf(pbcf(getcf(coords, zat) - cn, bx, bi));
    f3 ux = normf(pbcf(getcf(coords, xat) - cn, bx, bi));
    f3 zax = (m == 0) ? normf(uz + ux) : uz;
    f3 xax = normf(ux - zax * dotf(ux, zax));
    f3 yax = crossf(zax, xax);
    R[0][0] = xax.x; R[0][1] = yax.x; R[0][2] = zax.x;
    R[1][0] = xax.y; R[1][1] = yax.y; R[1][2] = zax.y;
    R[2][0] = xax.z; R[2][1] = yax.z; R[2][2] = zax.z;
    *tt = (m == 0) ? 0 : 1;
}

// rotated multipoles: M = [mu0,mu1,mu2, Qxx,Qxy,Qxz,Qyy,Qyz,Qzz]
__device__ inline void rot_muQ(const float R[3][3], int t, float M[9]) {
    float d0 = TF(DIP0_, t), d2 = TF(DIP2_, t);
    M[0] = R[0][0] * d0 + R[0][2] * d2;
    M[1] = R[1][0] * d0 + R[1][2] * d2;
    M[2] = R[2][0] * d0 + R[2][2] * d2;
    float qlxx = TF(QLXX_, t), qlyy = TF(QLYY_, t), qlzz = TF(QLZZ_, t), qlxz = TF(QLXZ_, t);
    float Bq[3][3];
    for (int p = 0; p < 3; ++p) {
        Bq[p][0] = R[p][0] * qlxx + R[p][2] * qlxz;
        Bq[p][1] = R[p][1] * qlyy;
        Bq[p][2] = R[p][0] * qlxz + R[p][2] * qlzz;
    }
    M[3] = Bq[0][0] * R[0][0] + Bq[0][1] * R[0][1] + Bq[0][2] * R[0][2];
    M[4] = Bq[0][0] * R[1][0] + Bq[0][1] * R[1][1] + Bq[0][2] * R[1][2];
    M[5] = Bq[0][0] * R[2][0] + Bq[0][1] * R[2][1] + Bq[0][2] * R[2][2];
    M[6] = Bq[1][0] * R[1][0] + Bq[1][1] * R[1][1] + Bq[1][2] * R[1][2];
    M[7] = Bq[1][0] * R[2][0] + Bq[1][1] * R[2][1] + Bq[1][2] * R[2][2];
    M[8] = Bq[2][0] * R[2][0] + Bq[2][1] * R[2][1] + Bq[2][2] * R[2][2];
}

__device__ inline float wredf(float v) {
    for (int off = 32; off > 0; off >>= 1) v += __shfl_xor(v, off);
    return v;
}
__device__ inline double wredd(double v) {
    for (int off = 32; off > 0; off >>= 1) v += __shfl_xor(v, off);
    return v;
}

// ws layout: partial[N] doubles | flag[N] ints
// =============== single kernel: block(256, 4 waves) per atom + spin-flag reduce ======
__global__ void __launch_bounds__(256, 3)
k_main(const float* __restrict__ coords, const float* __restrict__ box,
       double* __restrict__ wsd, int* __restrict__ flags,
       float* __restrict__ out, int N) {
    __shared__ float4 sh_list[MAXN];      // per-wave compacted (dr, b) segments
    __shared__ float  sh_muQ[MAXN * 9];   // multipoles of survivors, slot-parallel
    __shared__ double sh_red[NWAVE * 5];

    int a = blockIdx.x;
    int tid = threadIdx.x;
    int w = tid >> 6, lane = tid & 63;
    float bx[3][3], bi[3][3];
    load_boxf(box, bx, bi);

    int wa = a / 3;
    int ta = (a - wa * 3) ? 1 : 0;
    f3 ca = getcf(coords, a);

    // own-atom frame + multipoles (uniform across block)
    float Ra[3][3]; int tt0;
    calc_frame(coords, bx, bi, a, Ra, &tt0);
    float MA[9];
    rot_muQ(Ra, ta, MA);
    f3 mua = {MA[0], MA[1], MA[2]};
    float Qaxx = MA[3], Qaxy = MA[4], Qaxz = MA[5], Qayy = MA[6], Qayz = MA[7], Qazz = MA[8];

    // ---- phase 1: per-wave cutoff compaction into own LDS segment ----
    int chunks = (N + 64 * NWAVE - 1) / (64 * NWAVE);
    int seg = chunks * 64;
    int base = w * seg;
    int cnt = 0;
    for (int k = 0; k < chunks; ++k) {
        int b = base + k * 64 + lane;
        bool pred = false;
        f3 dr = {0.f, 0.f, 0.f};
        if (b < N) {
            int wb = b / 3;
            dr = pbcf(getcf(coords, b) - ca, bx, bi);
            pred = (wb != wa) && (dotf(dr, dr) < RCUT2F);
        }
        unsigned long long mask = __ballot(pred);
        int pref = __popcll(mask & ((1ull << lane) - 1ull));
        if (pred) sh_list[base + cnt + pref] = make_float4(dr.x, dr.y, dr.z, __int_as_float(b));
        cnt += __popcll(mask);
    }

    // ---- phase 1b: multipoles for SURVIVORS only (wave-local slots) ----
    for (int i = lane; i < cnt; i += 64) {
        int b = __float_as_int(sh_list[base + i].w);
        float Rb[3][3]; int tb;
        calc_frame(coords, bx, bi, b, Rb, &tb);
        float MB[9];
        rot_muQ(Rb, tb, MB);
        float* dst = &sh_muQ[(base + i) * 9];
        for (int k = 0; k < 9; ++k) dst[k] = MB[k];
    }

    // ---- type-pair dual constants ----
    float Zi = TF(Zc_, ta), qi = TF(QSH_, ta), qti = Zi + qi;
    float beli = TF(B_EL_, ta);
    float belj0 = (float)B_EL_[0], belj1 = (float)B_EL_[1];
    float bije0 = sqrtf(beli * belj0), bije1 = sqrtf(beli * belj1);
    float qtj0 = (float)(Zc_[0] + QSH_[0]), qtj1 = (float)(Zc_[1] + QSH_[1]);
    float Ziqj0 = Zi * (float)QSH_[0], Ziqj1 = Zi * (float)QSH_[1];
    float Zjqi0 = (float)Zc_[0] * qi, Zjqi1 = (float)Zc_[1] * qi;
    float qiqj0 = qi * (float)QSH_[0], qiqj1 = qi * (float)QSH_[1];
    float qq0 = qti * qtj0, qq1 = qti * qtj1;
    float sacci = TF(SACC_, ta);
    float saccj0 = (float)SACC_[0], saccj1 = (float)SACC_[1];
    float sdi = TF(SDON_, ta), kddi = TF(KD_DO_, ta), kqdi = TF(KQ_DO_, ta);
    float sdj0 = (float)SDON_[0], sdj1 = (float)SDON_[1];
    float kddj0 = (float)KD_DO_[0], kddj1 = (float)KD_DO_[1];
    float kqdj0 = (float)KQ_DO_[0], kqdj1 = (float)KQ_DO_[1];
    float bctt = TF(B_CT_, ta);
    float bijct0 = sqrtf(bctt * (float)B_CT_[0]), bijct1 = sqrtf(bctt * (float)B_CT_[1]);
    float inve0 = (ta == 0) ? 1e-15f : (float)(1.0 / EPS_OFF);
    float inve1 = (ta == 1) ? 1e-15f : (float)(1.0 / EPS_OFF);
    float spi = TF(SPA_, ta), kdpi = TF(KD_PA_, ta), kqpi = TF(KQ_PA_, ta);
    float spj0 = (float)SPA_[0], spj1 = (float)SPA_[1];
    float kdpj0 = (float)KD_PA_[0], kdpj1 = (float)KD_PA_[1];
    float kqpj0 = (float)KQ_PA_[0], kqpj1 = (float)KQ_PA_[1];
    float bpat = TF(B_PA_, ta);
    float bijpa0 = sqrtf(bpat * (float)B_PA_[0]), bijpa1 = sqrtf(bpat * (float)B_PA_[1]);
    float bxpt = TF(B_XP_, ta);
    float bijxp0 = sqrtf(bxpt * (float)B_XP_[0]), bijxp1 = sqrtf(bxpt * (float)B_XP_[1]);
    float sxpi = TF(SXP_, ta);
    float cxp0 = sxpi * (float)SXP_[0], cxp1 = sxpi * (float)SXP_[1];
    float bdt = TF(B_D_, ta);
    float bijd0 = sqrtf(bdt * (float)B_D_[0]), bijd1 = sqrtf(bdt * (float)B_D_[1]);
    float c6t = TF(C6_, ta);
    float c60 = sqrtf(c6t * (float)C6_[0]), c61 = sqrtf(c6t * (float)C6_[1]);

    // ---- phase 2: dense pair loop over this wave's survivors (f32 accum) ----
    float e = 0.f, efx = 0.f, efy = 0.f, efz = 0.f, dqa = 0.f;
    for (int i = lane; i < cnt; i += 64) {
        float4 E4 = sh_list[base + i];
        f3 dr = {E4.x, E4.y, E4.z};
        int b = __float_as_int(E4.w);
        int wb = b / 3;
        int tb = (b - wb * 3) ? 1 : 0;
        float r2 = dotf(dr, dr);
        float invr = rsqrtf(r2);
        float r = r2 * invr;
        f3 nv = dr * invr;
        float invr2 = invr * invr, invr3 = invr2 * invr;

        const float* MB = &sh_muQ[(base + i) * 9];
        f3 mub = {MB[0], MB[1], MB[2]};
        float muin = dotf(mua, nv), mujn = dotf(mub, nv);
        float nQni = Qaxx * nv.x * nv.x + Qayy * nv.y * nv.y + Qazz * nv.z * nv.z +
                     2.f * (Qaxy * nv.x * nv.y + Qaxz * nv.x * nv.z + Qayz * nv.y * nv.z);
        float nQnj = MB[3] * nv.x * nv.x + MB[6] * nv.y * nv.y + MB[8] * nv.z * nv.z +
                     2.f * (MB[4] * nv.x * nv.y + MB[5] * nv.x * nv.z + MB[7] * nv.y * nv.z);

        // permanent electrostatics (e_qq rearranged: no large-term cancellation)
        float fdm = f1mf(S(bije) * r);
        float fd = 1.f + fdm;
        float ep = (S(qq) + S(Ziqj) * f1mf(S(belj) * r) + S(Zjqi) * f1mf(beli * r) +
                    S(qiqj) * fdm) * invr;
        ep += fd * (S(qtj) * muin - qti * mujn) * invr2;
        ep += fd * (dotf(mua, mub) - 3.f * muin * mujn) * invr3;
        ep += 3.f * fd * (qti * nQnj + S(qtj) * nQni) * invr3;

        // field at atom a
        float cc = -S(qtj) * invr2 + 3.f * mujn * invr3;
        efx += fd * (cc * nv.x - mub.x * invr3);
        efy += fd * (cc * nv.y - mub.y * invr3);
        efz += fd * (cc * nv.z - mub.z * invr3);

        // charge transfer
        float sdon_i = sdi + kddi * muin + kqdi * nQni;
        float sdon_j = S(sdj) - S(kddj) * mujn + S(kqdj) * nQnj;
        float sct_r = __expf(-S(bijct) * r) * invr;
        ep -= (sdon_i * S(saccj) + sdon_j * sacci) * sct_r;
        dqa += sdon_j * sacci * sct_r * S(inve);

        // Pauli repulsion
        float si = spi + kdpi * muin + kqpi * nQni;
        float sj = S(spj) - S(kdpj) * mujn + S(kqpj) * nQnj;
        ep += si * sj * __expf(-S(bijpa) * r) * invr;

        // exchange polarization
        ep -= S(cxp) * __expf(-S(bijxp) * r) * invr;

        // Tang-Toennies dispersion
        float u = S(bijd) * r;
        float poly = 1.f + u * (1.f + u * (0.5f + u * (0.16666667f + u * (4.1666667e-2f +
                     u * (8.3333333e-3f + u * 1.3888889e-3f)))));
        ep -= (1.f - __expf(-u) * poly) * S(c6) * invr3 * invr3;

        e += ep;
    }

    // ---- reduction: wave shuffle (f32), then cross-wave via LDS (f64) ----
    e = wredf(e); efx = wredf(efx); efy = wredf(efy); efz = wredf(efz); dqa = wredf(dqa);
    if (lane == 0) {
        sh_red[w * 5 + 0] = (double)e;
        sh_red[w * 5 + 1] = (double)efx;
        sh_red[w * 5 + 2] = (double)efy;
        sh_red[w * 5 + 3] = (double)efz;
        sh_red[w * 5 + 4] = (double)dqa;
    }
    __syncthreads();

    if (tid == 0) {
        double se = 0, sx = 0, sy = 0, sz = 0, sq = 0;
        for (int k = 0; k < NWAVE; ++k) {
            se += sh_red[k * 5 + 0];
            sx += sh_red[k * 5 + 1];
            sy += sh_red[k * 5 + 2];
            sz += sh_red[k * 5 + 3];
            sq += sh_red[k * 5 + 4];
        }
        double tot = 0.5 * se;
        // polarization: -1/2 E.alpha.E, alpha = Ra diag Ra^T  -> v = Ra^T E
        double v0 = (double)Ra[0][0] * sx + (double)Ra[1][0] * sy + (double)Ra[2][0] * sz;
        double v1 = (double)Ra[0][1] * sx + (double)Ra[1][1] * sy + (double)Ra[2][1] * sz;
        double v2 = (double)Ra[0][2] * sx + (double)Ra[1][2] * sy + (double)Ra[2][2] * sz;
        tot -= 0.5 * ((ta ? AD_[1][0] : AD_[0][0]) * v0 * v0 +
                      (ta ? AD_[1][1] : AD_[0][1]) * v1 * v1 +
                      (ta ? AD_[1][2] : AD_[0][2]) * v2 * v2);
        // indirect charge transfer
        tot += 0.5 * (ta ? ETA_[1] : ETA_[0]) * sq * sq;

        // bonded terms: O-blocks handle their water (f64)
        if (ta == 0) {
            double bxd[3][3], bid[3][3];
            load_boxd(box, bxd, bid);
            d3 cO = getcd(coords, 3 * wa);
            d3 b1 = pbcd(subd(getcd(coords, 3 * wa + 1), cO), bxd, bid);
            d3 b2 = pbcd(subd(getcd(coords, 3 * wa + 2), cO), bxd, bid);
            double l1 = sqrt(dotd(b1, b1)), l2 = sqrt(dotd(b2, b2));
            double beta = sqrt(K_B / (2.0 * D_M));
            double x1 = 1.0 - exp(-beta * (l1 - B_EQ));
            double x2 = 1.0 - exp(-beta * (l2 - B_EQ));
            tot += D_M * (x1 * x1 + x2 * x2);
            tot += K_BB * (l1 - B_EQ) * (l2 - B_EQ);
            double cang = dotd(b1, b2) / (l1 * l2);
            cang = fmin(fmax(cang, -1.0 + 1e-7), 1.0 - 1e-7);
            double th = acos(cang);
            double cte = cos(TH_EQ);
            tot += 0.5 * K_TH * (cang - cte) * (cang - cte);
            tot += K_BA * ((l1 - B_EQ) + (l2 - B_EQ)) * (th - TH_EQ);
        }
        // publish partial: device-scope atomics (cross-XCD coherent), release fence, flag
        atomicExch((unsigned long long*)&wsd[a],
                   (unsigned long long)__double_as_longlong(tot));
        __threadfence();
        atomicExch(&flags[a], MAGIC);
    }

    // ---- block 0: spin-wait all flags, deterministic final reduce, reset flags ----
    if (a == 0) {
        __syncthreads();
        double v = 0.0;
        for (int i = tid; i < N; i += 256) {
            while (atomicAdd(&flags[i], 0) != MAGIC) __builtin_amdgcn_s_sleep(2);
            unsigned long long bits = atomicAdd((unsigned long long*)&wsd[i], 0ull);
            v += __longlong_as_double((long long)bits);   // fixed per-thread order
        }
        v = wredd(v);                                      // fixed shuffle tree
        __shared__ double s2[4];
        if (lane == 0) s2[w] = v;
        __syncthreads();
        // reset flags for the next (replayed) call — self-cleaning, replay-safe
        for (int i = tid; i < N; i += 256) atomicExch(&flags[i], 0);
        if (tid == 0) out[0] = (float)(s2[0] + s2[1] + s2[2] + s2[3]);
    }
}

extern "C" void kernel_launch(void* const* d_in, const int* in_sizes, int n_in,
                              void* d_out, int out_size, void* d_ws, size_t ws_size,
                              hipStream_t stream) {
    const float* coords = (const float*)d_in[0];
    const float* box    = (const float*)d_in[1];
    int N = in_sizes[0] / 3;  // atoms (768)
    double* wsd = (double*)d_ws;
    int* flags = (int*)(wsd + N);
    float* out = (float*)d_out;

    k_main<<<N, 256, 0, stream>>>(coords, box, wsd, flags, out, N);
}

// Round 10
// 16.910 us; speedup vs baseline: 5.0961x; 1.4000x over previous
//
#include <hip/hip_runtime.h>
#include <math.h>

// ---------------- constants (atomic units) ----------------
constexpr double B2A   = 0.52917721067;
constexpr double H2KJ  = 2625.499638;
constexpr float  RCUT2F = (float)((10.0 / B2A) * (10.0 / B2A));

constexpr double Zc_[2]   = {3.61565, 0.93619};
constexpr double MONO_[2] = {-0.390896, 0.195448};
constexpr double QSH_[2]  = {MONO_[0] - Zc_[0], MONO_[1] - Zc_[1]};
constexpr double DIPO_[2][3] = {{0.0, 0.0, -0.094298},
                                {0.0910288, 0.0, -0.207851}};
constexpr double QS_[2][5] = {{-0.330685, 0.0, 0.0, 0.869923, 0.0},
                              {-0.0739388, 0.0929482, 0.0, 0.00532425, 0.0}};
constexpr double B_EL_[2]  = {2.13358, 2.33322};
constexpr double B_PA_[2]  = {2.1975, 1.96474};
constexpr double SPA_[2]   = {6.50923, 0.527804};
constexpr double KD_PA_[2] = {-5.61925, -0.515584};
constexpr double KQ_PA_[2] = {-1.56567, -0.440164};
constexpr double C6_[2]    = {35.8289, 1.98954};
constexpr double B_D_[2]   = {1.84302, 1.30993};
constexpr double AD_[2][3] = {{4.45992, 6.07259, 4.55391},
                              {2.22001, 1.66835, 0.183855}};
constexpr double ETA_[2]   = {6.18699e-06 * 2.0, 0.561535 * 2.0};
constexpr double B_XP_[2]  = {2.73582, 2.04028};
constexpr double SXP_[2]   = {1.26592, 0.200089};
constexpr double B_CT_[2]  = {1.89485, 2.36763};
constexpr double SACC_[2]  = {-0.67857, 1.36735};
constexpr double SDON_[2]  = {0.757752, 0.00888982};
constexpr double KD_DO_[2] = {-0.512036, -0.0511668};
constexpr double KQ_DO_[2] = {-0.208186, 0.0568152};
constexpr double EPS_OFF = 0.380979;

constexpr double D_M   = 524.265 / H2KJ;
constexpr double K_B   = 5098.15 / H2KJ * B2A * B2A;
constexpr double B_EQ  = 0.958413 / B2A;
constexpr double K_BB  = -61.1423 / H2KJ * B2A * B2A;
constexpr double K_BA  = -159.886 / H2KJ * B2A;
constexpr double TH_EQ = 104.4234 * M_PI / 180.0;
constexpr double K_TH  = 452.183 / H2KJ;
constexpr double SQ32  = 0.86602540378443864676;

// local-frame quadrupole (traceless Cartesian), /3 folded; q21s=q22s=0 -> only xx,yy,zz,xz
constexpr double QLXX_[2] = {(-0.5 * QS_[0][0] + SQ32 * QS_[0][3]) / 3.0,
                             (-0.5 * QS_[1][0] + SQ32 * QS_[1][3]) / 3.0};
constexpr double QLYY_[2] = {(-0.5 * QS_[0][0] - SQ32 * QS_[0][3]) / 3.0,
                             (-0.5 * QS_[1][0] - SQ32 * QS_[1][3]) / 3.0};
constexpr double QLZZ_[2] = {QS_[0][0] / 3.0, QS_[1][0] / 3.0};
constexpr double QLXZ_[2] = {SQ32 * QS_[0][1] / 3.0, SQ32 * QS_[1][1] / 3.0};
constexpr double DIP0_[2] = {DIPO_[0][0], DIPO_[1][0]};
constexpr double DIP2_[2] = {DIPO_[0][2], DIPO_[1][2]};

#define MAXN 768
#define NWAVE 4
#define TF(A, t) ((t) ? (float)A[1] : (float)A[0])
#define S(x) (tb ? x##1 : x##0)

// ---------------- f32 vec helpers ----------------
struct f3 { float x, y, z; };
__device__ inline f3 operator-(f3 a, f3 b) { return {a.x - b.x, a.y - b.y, a.z - b.z}; }
__device__ inline f3 operator+(f3 a, f3 b) { return {a.x + b.x, a.y + b.y, a.z + b.z}; }
__device__ inline f3 operator*(f3 a, float s) { return {a.x * s, a.y * s, a.z * s}; }
__device__ inline float dotf(f3 a, f3 b) { return a.x * b.x + a.y * b.y + a.z * b.z; }
__device__ inline f3 crossf(f3 a, f3 b) {
    return {a.y * b.z - a.z * b.y, a.z * b.x - a.x * b.z, a.x * b.y - a.y * b.x};
}
__device__ inline f3 normf(f3 a) { float s = rsqrtf(dotf(a, a)); return a * s; }
__device__ inline f3 getcf(const float* c, int i) {
    return {c[3 * i], c[3 * i + 1], c[3 * i + 2]};
}

// box context: general 3x3 + fast diagonal path (uniform runtime select)
struct BoxF {
    float bx[3][3], bi[3][3];
    float Lx, Ly, Lz, iLx, iLy, iLz;
    bool diag;
};
__device__ inline void load_boxctx(const float* box, BoxF& B) {
    for (int i = 0; i < 3; ++i)
        for (int j = 0; j < 3; ++j) B.bx[i][j] = box[i * 3 + j];
    B.diag = (box[1] == 0.f && box[2] == 0.f && box[3] == 0.f &&
              box[5] == 0.f && box[6] == 0.f && box[7] == 0.f);
    float a = B.bx[0][0], b = B.bx[0][1], c = B.bx[0][2];
    float d = B.bx[1][0], e = B.bx[1][1], f = B.bx[1][2];
    float g = B.bx[2][0], h = B.bx[2][1], i2 = B.bx[2][2];
    float A =  (e * i2 - f * h), Bb = -(d * i2 - f * g), C =  (d * h - e * g);
    float D = -(b * i2 - c * h), E =  (a * i2 - c * g), F = -(a * h - b * g);
    float G =  (b * f - c * e),  H = -(a * f - c * d),  I =  (a * e - b * d);
    float s = 1.0f / (a * A + b * Bb + c * C);
    B.bi[0][0] = A * s;  B.bi[0][1] = D * s; B.bi[0][2] = G * s;
    B.bi[1][0] = Bb * s; B.bi[1][1] = E * s; B.bi[1][2] = H * s;
    B.bi[2][0] = C * s;  B.bi[2][1] = F * s; B.bi[2][2] = I * s;
    B.Lx = B.bx[0][0]; B.Ly = B.bx[1][1]; B.Lz = B.bx[2][2];
    B.iLx = 1.f / B.Lx; B.iLy = 1.f / B.Ly; B.iLz = 1.f / B.Lz;
}
__device__ inline f3 pbcf(f3 d, const BoxF& B) {
    if (B.diag) {   // uniform branch
        d.x -= rintf(d.x * B.iLx) * B.Lx;
        d.y -= rintf(d.y * B.iLy) * B.Ly;
        d.z -= rintf(d.z * B.iLz) * B.Lz;
        return d;
    }
    float s0 = rintf(d.x * B.bi[0][0] + d.y * B.bi[1][0] + d.z * B.bi[2][0]);
    float s1 = rintf(d.x * B.bi[0][1] + d.y * B.bi[1][1] + d.z * B.bi[2][1]);
    float s2 = rintf(d.x * B.bi[0][2] + d.y * B.bi[1][2] + d.z * B.bi[2][2]);
    d.x -= s0 * B.bx[0][0] + s1 * B.bx[1][0] + s2 * B.bx[2][0];
    d.y -= s0 * B.bx[0][1] + s1 * B.bx[1][1] + s2 * B.bx[2][1];
    d.z -= s0 * B.bx[0][2] + s1 * B.bx[1][2] + s2 * B.bx[2][2];
    return d;
}
__device__ inline float f1mf(float u) { return -__expf(-u) * (1.0f + 0.5f * u); }  // f1 - 1

// ---------------- frame (local axes) ----------------
__device__ inline void calc_frame(const float* coords, const BoxF& B,
                                  int n, float R[3][3], int* tt) {
    int w = n / 3, m = n - w * 3, o = w * 3;
    int zat = (m == 0) ? n + 1 : o;
    int xat = (m == 0) ? n + 2 : ((m == 1) ? n + 1 : n - 1);
    f3 cn = getcf(coords, n);
    f3 uz = normf(pbcf(getcf(coords, zat) - cn, B));
    f3 ux = normf(pbcf(getcf(coords, xat) - cn, B));
    f3 zax = (m == 0) ? normf(uz + ux) : uz;
    f3 xax = normf(ux - zax * dotf(ux, zax));
    f3 yax = crossf(zax, xax);
    R[0][0] = xax.x; R[0][1] = yax.x; R[0][2] = zax.x;
    R[1][0] = xax.y; R[1][1] = yax.y; R[1][2] = zax.y;
    R[2][0] = xax.z; R[2][1] = yax.z; R[2][2] = zax.z;
    *tt = (m == 0) ? 0 : 1;
}

// rotated multipoles: M = [mu0,mu1,mu2, Qxx,Qxy,Qxz,Qyy,Qyz,Qzz]
__device__ inline void rot_muQ(const float R[3][3], int t, float M[9]) {
    float d0 = TF(DIP0_, t), d2 = TF(DIP2_, t);
    M[0] = R[0][0] * d0 + R[0][2] * d2;
    M[1] = R[1][0] * d0 + R[1][2] * d2;
    M[2] = R[2][0] * d0 + R[2][2] * d2;
    float qlxx = TF(QLXX_, t), qlyy = TF(QLYY_, t), qlzz = TF(QLZZ_, t), qlxz = TF(QLXZ_, t);
    float Bq[3][3];
    for (int p = 0; p < 3; ++p) {
        Bq[p][0] = R[p][0] * qlxx + R[p][2] * qlxz;
        Bq[p][1] = R[p][1] * qlyy;
        Bq[p][2] = R[p][0] * qlxz + R[p][2] * qlzz;
    }
    M[3] = Bq[0][0] * R[0][0] + Bq[0][1] * R[0][1] + Bq[0][2] * R[0][2];
    M[4] = Bq[0][0] * R[1][0] + Bq[0][1] * R[1][1] + Bq[0][2] * R[1][2];
    M[5] = Bq[0][0] * R[2][0] + Bq[0][1] * R[2][1] + Bq[0][2] * R[2][2];
    M[6] = Bq[1][0] * R[1][0] + Bq[1][1] * R[1][1] + Bq[1][2] * R[1][2];
    M[7] = Bq[1][0] * R[2][0] + Bq[1][1] * R[2][1] + Bq[1][2] * R[2][2];
    M[8] = Bq[2][0] * R[2][0] + Bq[2][1] * R[2][1] + Bq[2][2] * R[2][2];
}

__device__ inline float wredf(float v) {
    for (int off = 32; off > 0; off >>= 1) v += __shfl_xor(v, off);
    return v;
}
__device__ inline double wredd(double v) {
    for (int off = 32; off > 0; off >>= 1) v += __shfl_xor(v, off);
    return v;
}

// =============== kernel 1: block(256, 4 waves) per atom ===============
__global__ void __launch_bounds__(256, 3)
k_main(const float* __restrict__ coords, const float* __restrict__ box,
       double* __restrict__ wsd, int N) {
    __shared__ float4 sh_list[MAXN];      // per-wave compacted (dr, b) segments
    __shared__ float  sh_muQ[MAXN * 9];   // multipoles of survivors, slot-parallel
    __shared__ double sh_red[NWAVE * 5];

    int a = blockIdx.x;
    int tid = threadIdx.x;
    int w = tid >> 6, lane = tid & 63;
    BoxF B;
    load_boxctx(box, B);

    int wa = a / 3;
    int ta = (a - wa * 3) ? 1 : 0;
    f3 ca = getcf(coords, a);

    // own-atom frame + multipoles (uniform across block)
    float Ra[3][3]; int tt0;
    calc_frame(coords, B, a, Ra, &tt0);
    float MA[9];
    rot_muQ(Ra, ta, MA);
    f3 mua = {MA[0], MA[1], MA[2]};
    float Qaxx = MA[3], Qaxy = MA[4], Qaxz = MA[5], Qayy = MA[6], Qayz = MA[7], Qazz = MA[8];

    // ---- phase 1: per-wave cutoff compaction into own LDS segment ----
    int chunks = (N + 64 * NWAVE - 1) / (64 * NWAVE);
    int seg = chunks * 64;
    int base = w * seg;
    int cnt = 0;
    for (int k = 0; k < chunks; ++k) {
        int b = base + k * 64 + lane;
        bool pred = false;
        f3 dr = {0.f, 0.f, 0.f};
        if (b < N) {
            int wb = b / 3;
            dr = pbcf(getcf(coords, b) - ca, B);
            pred = (wb != wa) && (dotf(dr, dr) < RCUT2F);
        }
        unsigned long long mask = __ballot(pred);
        int pref = __popcll(mask & ((1ull << lane) - 1ull));
        if (pred) sh_list[base + cnt + pref] = make_float4(dr.x, dr.y, dr.z, __int_as_float(b));
        cnt += __popcll(mask);
    }

    // ---- phase 1b: multipoles for SURVIVORS only (wave-local slots) ----
    for (int i = lane; i < cnt; i += 64) {
        int b = __float_as_int(sh_list[base + i].w);
        float Rb[3][3]; int tb;
        calc_frame(coords, B, b, Rb, &tb);
        float MB[9];
        rot_muQ(Rb, tb, MB);
        float* dst = &sh_muQ[(base + i) * 9];
        for (int k = 0; k < 9; ++k) dst[k] = MB[k];
    }

    // ---- type-pair dual constants ----
    float Zi = TF(Zc_, ta), qi = TF(QSH_, ta), qti = Zi + qi;
    float beli = TF(B_EL_, ta);
    float belj0 = (float)B_EL_[0], belj1 = (float)B_EL_[1];
    float bije0 = sqrtf(beli * belj0), bije1 = sqrtf(beli * belj1);
    float qtj0 = (float)(Zc_[0] + QSH_[0]), qtj1 = (float)(Zc_[1] + QSH_[1]);
    float Ziqj0 = Zi * (float)QSH_[0], Ziqj1 = Zi * (float)QSH_[1];
    float Zjqi0 = (float)Zc_[0] * qi, Zjqi1 = (float)Zc_[1] * qi;
    float qiqj0 = qi * (float)QSH_[0], qiqj1 = qi * (float)QSH_[1];
    float qq0 = qti * qtj0, qq1 = qti * qtj1;
    float sacci = TF(SACC_, ta);
    float saccj0 = (float)SACC_[0], saccj1 = (float)SACC_[1];
    float sdi = TF(SDON_, ta), kddi = TF(KD_DO_, ta), kqdi = TF(KQ_DO_, ta);
    float sdj0 = (float)SDON_[0], sdj1 = (float)SDON_[1];
    float kddj0 = (float)KD_DO_[0], kddj1 = (float)KD_DO_[1];
    float kqdj0 = (float)KQ_DO_[0], kqdj1 = (float)KQ_DO_[1];
    float bctt = TF(B_CT_, ta);
    float bijct0 = sqrtf(bctt * (float)B_CT_[0]), bijct1 = sqrtf(bctt * (float)B_CT_[1]);
    float inve0 = (ta == 0) ? 1e-15f : (float)(1.0 / EPS_OFF);
    float inve1 = (ta == 1) ? 1e-15f : (float)(1.0 / EPS_OFF);
    float spi = TF(SPA_, ta), kdpi = TF(KD_PA_, ta), kqpi = TF(KQ_PA_, ta);
    float spj0 = (float)SPA_[0], spj1 = (float)SPA_[1];
    float kdpj0 = (float)KD_PA_[0], kdpj1 = (float)KD_PA_[1];
    float kqpj0 = (float)KQ_PA_[0], kqpj1 = (float)KQ_PA_[1];
    float bpat = TF(B_PA_, ta);
    float bijpa0 = sqrtf(bpat * (float)B_PA_[0]), bijpa1 = sqrtf(bpat * (float)B_PA_[1]);
    float bxpt = TF(B_XP_, ta);
    float bijxp0 = sqrtf(bxpt * (float)B_XP_[0]), bijxp1 = sqrtf(bxpt * (float)B_XP_[1]);
    float sxpi = TF(SXP_, ta);
    float cxp0 = sxpi * (float)SXP_[0], cxp1 = sxpi * (float)SXP_[1];
    float bdt = TF(B_D_, ta);
    float bijd0 = sqrtf(bdt * (float)B_D_[0]), bijd1 = sqrtf(bdt * (float)B_D_[1]);
    float c6t = TF(C6_, ta);
    float c60 = sqrtf(c6t * (float)C6_[0]), c61 = sqrtf(c6t * (float)C6_[1]);

    // ---- phase 2: dense pair loop over this wave's survivors (f32 accum) ----
    float e = 0.f, efx = 0.f, efy = 0.f, efz = 0.f, dqa = 0.f;
    for (int i = lane; i < cnt; i += 64) {
        float4 E4 = sh_list[base + i];
        f3 dr = {E4.x, E4.y, E4.z};
        int b = __float_as_int(E4.w);
        int wb = b / 3;
        int tb = (b - wb * 3) ? 1 : 0;
        float r2 = dotf(dr, dr);
        float invr = rsqrtf(r2);
        float r = r2 * invr;
        f3 nv = dr * invr;
        float invr2 = invr * invr, invr3 = invr2 * invr;

        const float* MB = &sh_muQ[(base + i) * 9];
        f3 mub = {MB[0], MB[1], MB[2]};
        float muin = dotf(mua, nv), mujn = dotf(mub, nv);
        float nQni = Qaxx * nv.x * nv.x + Qayy * nv.y * nv.y + Qazz * nv.z * nv.z +
                     2.f * (Qaxy * nv.x * nv.y + Qaxz * nv.x * nv.z + Qayz * nv.y * nv.z);
        float nQnj = MB[3] * nv.x * nv.x + MB[6] * nv.y * nv.y + MB[8] * nv.z * nv.z +
                     2.f * (MB[4] * nv.x * nv.y + MB[5] * nv.x * nv.z + MB[7] * nv.y * nv.z);

        // permanent electrostatics (e_qq rearranged: no large-term cancellation)
        float fdm = f1mf(S(bije) * r);
        float fd = 1.f + fdm;
        float ep = (S(qq) + S(Ziqj) * f1mf(S(belj) * r) + S(Zjqi) * f1mf(beli * r) +
                    S(qiqj) * fdm) * invr;
        ep += fd * (S(qtj) * muin - qti * mujn) * invr2;
        ep += fd * (dotf(mua, mub) - 3.f * muin * mujn) * invr3;
        ep += 3.f * fd * (qti * nQnj + S(qtj) * nQni) * invr3;

        // field at atom a
        float cc = -S(qtj) * invr2 + 3.f * mujn * invr3;
        efx += fd * (cc * nv.x - mub.x * invr3);
        efy += fd * (cc * nv.y - mub.y * invr3);
        efz += fd * (cc * nv.z - mub.z * invr3);

        // charge transfer
        float sdon_i = sdi + kddi * muin + kqdi * nQni;
        float sdon_j = S(sdj) - S(kddj) * mujn + S(kqdj) * nQnj;
        float sct_r = __expf(-S(bijct) * r) * invr;
        ep -= (sdon_i * S(saccj) + sdon_j * sacci) * sct_r;
        dqa += sdon_j * sacci * sct_r * S(inve);

        // Pauli repulsion
        float si = spi + kdpi * muin + kqpi * nQni;
        float sj = S(spj) - S(kdpj) * mujn + S(kqpj) * nQnj;
        ep += si * sj * __expf(-S(bijpa) * r) * invr;

        // exchange polarization
        ep -= S(cxp) * __expf(-S(bijxp) * r) * invr;

        // Tang-Toennies dispersion
        float u = S(bijd) * r;
        float poly = 1.f + u * (1.f + u * (0.5f + u * (0.16666667f + u * (4.1666667e-2f +
                     u * (8.3333333e-3f + u * 1.3888889e-3f)))));
        ep -= (1.f - __expf(-u) * poly) * S(c6) * invr3 * invr3;

        e += ep;
    }

    // ---- reduction: wave shuffle (f32), then cross-wave via LDS (f64) ----
    e = wredf(e); efx = wredf(efx); efy = wredf(efy); efz = wredf(efz); dqa = wredf(dqa);
    if (lane == 0) {
        sh_red[w * 5 + 0] = (double)e;
        sh_red[w * 5 + 1] = (double)efx;
        sh_red[w * 5 + 2] = (double)efy;
        sh_red[w * 5 + 3] = (double)efz;
        sh_red[w * 5 + 4] = (double)dqa;
    }
    __syncthreads();

    if (tid == 0) {
        double se = 0, sx = 0, sy = 0, sz = 0, sq = 0;
        for (int k = 0; k < NWAVE; ++k) {
            se += sh_red[k * 5 + 0];
            sx += sh_red[k * 5 + 1];
            sy += sh_red[k * 5 + 2];
            sz += sh_red[k * 5 + 3];
            sq += sh_red[k * 5 + 4];
        }
        double tot = 0.5 * se;

        // ---- f32 tail (short chains; error budget ~1e-5 rel per atom) ----
        float sxf = (float)sx, syf = (float)sy, szf = (float)sz;
        // polarization: -1/2 E.alpha.E, alpha = Ra diag Ra^T  -> v = Ra^T E
        float v0 = Ra[0][0] * sxf + Ra[1][0] * syf + Ra[2][0] * szf;
        float v1 = Ra[0][1] * sxf + Ra[1][1] * syf + Ra[2][1] * szf;
        float v2 = Ra[0][2] * sxf + Ra[1][2] * syf + Ra[2][2] * szf;
        float ad0 = TF(AD_[0], 0), ad1 = TF(AD_[0], 0), ad2 = TF(AD_[0], 0); // placeholders
        ad0 = ta ? (float)AD_[1][0] : (float)AD_[0][0];
        ad1 = ta ? (float)AD_[1][1] : (float)AD_[0][1];
        ad2 = ta ? (float)AD_[1][2] : (float)AD_[0][2];
        float pol = -0.5f * (ad0 * v0 * v0 + ad1 * v1 * v1 + ad2 * v2 * v2);
        // indirect charge transfer
        float dqf = (float)sq;
        float eta = ta ? (float)ETA_[1] : (float)ETA_[0];
        float ctind = 0.5f * eta * dqf * dqf;
        tot += (double)pol + (double)ctind;

        // bonded terms: O-blocks handle their water (f32 chains)
        if (ta == 0) {
            f3 cO = getcf(coords, 3 * wa);
            f3 b1 = pbcf(getcf(coords, 3 * wa + 1) - cO, B);
            f3 b2 = pbcf(getcf(coords, 3 * wa + 2) - cO, B);
            float l1 = sqrtf(dotf(b1, b1)), l2 = sqrtf(dotf(b2, b2));
            const float betaf = (float)(0.0);  // computed below (sqrt not constexpr)
            float bf = sqrtf((float)(K_B / (2.0 * D_M)));
            (void)betaf;
            float d1 = l1 - (float)B_EQ, d2 = l2 - (float)B_EQ;
            float x1 = 1.f - __expf(-bf * d1);
            float x2 = 1.f - __expf(-bf * d2);
            float eb = (float)D_M * (x1 * x1 + x2 * x2);
            eb += (float)K_BB * d1 * d2;
            float cang = dotf(b1, b2) / (l1 * l2);
            cang = fminf(fmaxf(cang, -1.f + 1e-7f), 1.f - 1e-7f);
            float th = acosf(cang);
            float cte = cosf((float)TH_EQ);
            float dc = cang - cte;
            eb += 0.5f * (float)K_TH * dc * dc;
            eb += (float)K_BA * (d1 + d2) * (th - (float)TH_EQ);
            tot += (double)eb;
        }
        wsd[a] = tot;   // deterministic per-atom partial
    }
}

// =============== kernel 2: deterministic final reduce ===============
__global__ void __launch_bounds__(256) k_final(const double* __restrict__ wsd,
                                               float* __restrict__ out, int N) {
    int tid = threadIdx.x;
    int w = tid >> 6, lane = tid & 63;
    double v = 0.0;
    for (int i = tid; i < N; i += 256) v += wsd[i];
    v = wredd(v);
    __shared__ double s[4];
    if (lane == 0) s[w] = v;
    __syncthreads();
    if (tid == 0) out[0] = (float)(s[0] + s[1] + s[2] + s[3]);
}

extern "C" void kernel_launch(void* const* d_in, const int* in_sizes, int n_in,
                              void* d_out, int out_size, void* d_ws, size_t ws_size,
                              hipStream_t stream) {
    const float* coords = (const float*)d_in[0];
    const float* box    = (const float*)d_in[1];
    int N = in_sizes[0] / 3;  // atoms (768)
    double* wsd = (double*)d_ws;
    float* out = (float*)d_out;

    k_main<<<N, 256, 0, stream>>>(coords, box, wsd, N);
    k_final<<<1, 256, 0, stream>>>(wsd, out, N);
}